// Round 11
// baseline (1866.139 us; speedup 1.0000x reference)
//
#include <hip/hip_runtime.h>
#include <hip/hip_bf16.h>
#include <cstddef>

// ---------------- problem constants ----------------
constexpr int cN_LOW  = 20000;
constexpr int cN_HIGH = 150000;
constexpr int cSEQ = 25;
constexpr int cHIN = 25;
constexpr int cHHID = 25;
constexpr int cENC = 32;
constexpr int cHIGH_IN = 7;
constexpr int cD = 16;
constexpr int cNL = 5;
constexpr int cE_L2H = 1350000;
constexpr int cE_HH = 1200000;
constexpr float cEPS = 1e-5f;
constexpr float cSLOPE = 0.2f;
constexpr float INV_NLOW  = 1.0f / (float)cN_LOW;
constexpr float INV_NHIGH = 1.0f / (float)cN_HIGH;

constexpr int cHSP = 640;     // padded hs row stride: 10 exact 64-f chunks

// scan geometry
constexpr int SC_ELEM = 1024;
constexpr int SC_NB   = (cN_HIGH + SC_ELEM - 1) / SC_ELEM;     // 147
static_assert(SC_NB <= 256, "top scan assumes <=256 partials");

// ---------------- workspace layout (4-byte element offsets) ----------------
constexpr size_t OFF_HS   = 0;                                   // [N_LOW*640]
constexpr size_t SZ_HS    = (size_t)cN_LOW * cHSP;
constexpr size_t OFF_AGG  = 0;                                   // alias (hs dead after k_dense)
constexpr size_t OFF_ENC  = OFF_HS + SZ_HS;                      // [N_LOW*32]
constexpr size_t SZ_ENC   = (size_t)cN_LOW * cENC;
constexpr size_t OFF_XA   = OFF_ENC + SZ_ENC;
constexpr size_t OFF_XB   = OFF_XA + (size_t)cN_HIGH * cD;
constexpr size_t OFF_XL   = OFF_XB + (size_t)cN_HIGH * cD;
constexpr size_t OFF_XR   = OFF_XL + (size_t)cN_HIGH * cD;
constexpr size_t OFF_STAT = OFF_XR + (size_t)cN_HIGH * cD;       // [256]
constexpr size_t OFF_RPH  = OFF_STAT + 256;                      // rowptr_hh [N_HIGH+4]
constexpr size_t OFF_SRH  = OFF_RPH + cN_HIGH + 4;               // src_hh [E_HH]
constexpr size_t OFF_RPL  = OFF_SRH + cE_HH;                     // rowptr_l2h [N_HIGH+4]
constexpr size_t OFF_SRL  = OFF_RPL + cN_HIGH + 4;               // src_l2h [E_L2H]
constexpr size_t OFF_CUR  = OFF_SRL + cE_L2H;                    // cursor [N_HIGH]
constexpr size_t OFF_PART = OFF_CUR + cN_HIGH;                   // partials [256]
constexpr size_t OFF_XLB  = OFF_PART + 256;                      // xl bf16 [N_HIGH*16 ushort = N_HIGH*8 floats]
constexpr size_t OFF_PERM = OFF_XLB + (size_t)cN_HIGH * 8;       // degree-sorted node perm [N_HIGH]
constexpr size_t OFF_BINS = OFF_PERM + cN_HIGH;                  // 64 degree bins

__device__ __forceinline__ float fast_sigmoid(float a) {
  return __builtin_amdgcn_rcpf(1.0f + __expf(-a));
}
__device__ __forceinline__ float fast_tanh(float a) {
  float t = __expf(-2.0f * a);
  return (1.0f - t) * __builtin_amdgcn_rcpf(1.0f + t);
}
__device__ __forceinline__ unsigned int f32_to_bf16_bits(float f) {
  unsigned int u = __float_as_uint(f);
  return (u + 0x7FFFu + ((u >> 16) & 1u)) >> 16;     // RNE
}

// ---------------- GRU kernel (gate-split, float4 broadcast vin reads) ----------------
// r10 counters: VGPR=56 (compiler reloads weights from L1 in-loop) and the
// kernel is LDS-pipe bound on 25 b32 vin reads/side/t. Rows padded to 28
// (16B-aligned) -> 7 b128 broadcast reads/t. Weight arrays padded to 28 with
// zeros so the FMA loop is uniform (pads: 0 * 0 = 0).
constexpr int GN = 5;                 // nodes per block
constexpr int GB = GN * 50;           // 250 threads

__global__ __launch_bounds__(256, 4)
void k_gru(const float* __restrict__ x_low,
           const float* __restrict__ Wih, const float* __restrict__ Whh,
           const float* __restrict__ bih, const float* __restrict__ bhh,
           float* __restrict__ hs) {
  __shared__ __align__(16) float sx[2][GN][28];
  __shared__ __align__(16) float sh[2][GN][28];
  __shared__ float sgi[GN][76];
  __shared__ float sgh[GN][76];

  int tid = threadIdx.x;
  int nl  = tid / 50;
  int rem = tid % 50;
  int s   = rem / 25;          // 0: x-side, 1: h-side
  int j   = rem % 25;
  int n   = blockIdx.x * GN + nl;

  const float* Wb = (s == 0) ? Wih : Whh;
  const float* bb = (s == 0) ? bih : bhh;
  float w0[28], w1[28], w2[28];
  #pragma unroll
  for (int i = 0; i < 28; ++i) {
    w0[i] = (i < 25) ? Wb[j * 25 + i] : 0.0f;
    w1[i] = (i < 25) ? Wb[(25 + j) * 25 + i] : 0.0f;
    w2[i] = (i < 25) ? Wb[(50 + j) * 25 + i] : 0.0f;
  }
  float b0 = bb[j], b1 = bb[25 + j], b2 = bb[50 + j];

  const float* xrow = x_low + (size_t)n * 625;
  float* hrow = hs + (size_t)n * cHSP;
  if (s == 0 && j < 15) hrow[625 + j] = 0.0f;   // zero hs pad for dense chunks
  if (s == 0 && j < 3) {                         // zero LDS row pads (both buffers)
    sx[0][nl][25 + j] = 0.0f; sx[1][nl][25 + j] = 0.0f;
    sh[0][nl][25 + j] = 0.0f; sh[1][nl][25 + j] = 0.0f;
  }
  if (s == 0) { sh[0][nl][j] = 0.0f; sx[0][nl][j] = xrow[j]; }
  __syncthreads();

  int p = 0, q = 0;
  for (int t = 0; t < cSEQ; ++t) {
    if (s == 0 && t + 1 < cSEQ) sx[q ^ 1][nl][j] = xrow[(t + 1) * 25 + j];
    const float4* vin4 = (const float4*)((s == 0) ? &sx[q][nl][0] : &sh[p][nl][0]);
    float g0 = b0, g1 = b1, g2 = b2;
    #pragma unroll
    for (int c = 0; c < 7; ++c) {
      float4 v = vin4[c];
      g0 += w0[4*c] * v.x + w0[4*c+1] * v.y + w0[4*c+2] * v.z + w0[4*c+3] * v.w;
      g1 += w1[4*c] * v.x + w1[4*c+1] * v.y + w1[4*c+2] * v.z + w1[4*c+3] * v.w;
      g2 += w2[4*c] * v.x + w2[4*c+1] * v.y + w2[4*c+2] * v.z + w2[4*c+3] * v.w;
    }
    float* gout = (s == 0) ? &sgi[nl][0] : &sgh[nl][0];
    gout[j] = g0; gout[25 + j] = g1; gout[50 + j] = g2;
    __syncthreads();
    if (s == 1) {
      float r  = fast_sigmoid(sgi[nl][j] + sgh[nl][j]);
      float z  = fast_sigmoid(sgi[nl][25 + j] + sgh[nl][25 + j]);
      float nn = fast_tanh(sgi[nl][50 + j] + r * sgh[nl][50 + j]);
      float hnew = (1.0f - z) * nn + z * sh[p][nl][j];
      sh[p ^ 1][nl][j] = hnew;
      hrow[t * 25 + j] = hnew;
    }
    p ^= 1; q ^= 1;
    __syncthreads();
  }
}

// ---------------- dense 625->32 + relu + BN stats (v4) ----------------
constexpr int cDN = 32;      // nodes per block
__global__ __launch_bounds__(256)
void k_dense(const float* __restrict__ hs, const float* __restrict__ W,
             const float* __restrict__ b, float* __restrict__ enc,
             float* __restrict__ statsEnc) {
  __shared__ __align__(16) float sW2[640 * 32];        // 80 KB: [f][e2-pair]
  __shared__ __align__(16) float sH[2][cDN * 68];      // 17.4 KB
  __shared__ float sstat[2 * cENC];
  int tid = threadIdx.x;
  for (int i = tid; i < 32 * 625; i += 256) {
    int e = i / 625, f = i % 625;
    sW2[f * 32 + (e & 15) * 2 + (e >> 4)] = W[i];
  }
  for (int i = tid; i < 32 * 15; i += 256)
    sW2[(625 + (i >> 5)) * 32 + (i & 31)] = 0.0f;
  if (tid < 2 * cENC) sstat[tid] = 0.0f;

  int e2 = tid & 15;
  int ng = (tid >> 4) & 3;
  int w  = tid >> 6;
  int rA = 8 * w + 2 * ng;
  int rB = rA + 1;
  size_t nbase = (size_t)blockIdx.x * cDN;

  int srow = tid >> 4;
  int sf4  = (tid & 15) * 4;
  const float* hsb = hs + nbase * cHSP;
  {
    float4 v0 = *(const float4*)(hsb + (size_t)srow * cHSP + sf4);
    float4 v1 = *(const float4*)(hsb + (size_t)(srow + 16) * cHSP + sf4);
    *(float4*)&sH[0][srow * 68 + sf4] = v0;
    *(float4*)&sH[0][(srow + 16) * 68 + sf4] = v1;
  }
  __syncthreads();

  float a00 = 0.0f, a01 = 0.0f, a10 = 0.0f, a11 = 0.0f;
  for (int c = 0; c < 10; ++c) {
    int buf = c & 1;
    if (c + 1 < 10) {
      const float* src = hsb + (c + 1) * 64;
      float4 v0 = *(const float4*)(src + (size_t)srow * cHSP + sf4);
      float4 v1 = *(const float4*)(src + (size_t)(srow + 16) * cHSP + sf4);
      *(float4*)&sH[buf ^ 1][srow * 68 + sf4] = v0;
      *(float4*)&sH[buf ^ 1][(srow + 16) * 68 + sf4] = v1;
    }
    const float* WC = sW2 + c * 64 * 32;
    #pragma unroll
    for (int fg = 0; fg < 16; ++fg) {
      float4 hA = *(const float4*)&sH[buf][rA * 68 + fg * 4];
      float4 hB = *(const float4*)&sH[buf][rB * 68 + fg * 4];
      const float* ha = (const float*)&hA;
      const float* hb = (const float*)&hB;
      #pragma unroll
      for (int k = 0; k < 4; ++k) {
        float2 wv = *(const float2*)&WC[(fg * 4 + k) * 32 + e2 * 2];
        a00 += wv.x * ha[k]; a01 += wv.y * ha[k];
        a10 += wv.x * hb[k]; a11 += wv.y * hb[k];
      }
    }
    __syncthreads();
  }
  float blo = b[e2], bhi = b[e2 + 16];
  float v00 = fmaxf(a00 + blo, 0.0f);
  float v01 = fmaxf(a01 + bhi, 0.0f);
  float v10 = fmaxf(a10 + blo, 0.0f);
  float v11 = fmaxf(a11 + bhi, 0.0f);
  size_t nA = nbase + rA, nB = nbase + rB;
  enc[nA * cENC + e2]      = v00;
  enc[nA * cENC + e2 + 16] = v01;
  enc[nB * cENC + e2]      = v10;
  enc[nB * cENC + e2 + 16] = v11;

  float s1lo = v00 + v10, s1hi = v01 + v11;
  float s2lo = v00 * v00 + v10 * v10, s2hi = v01 * v01 + v11 * v11;
  s1lo += __shfl_xor(s1lo, 16); s1hi += __shfl_xor(s1hi, 16);
  s2lo += __shfl_xor(s2lo, 16); s2hi += __shfl_xor(s2hi, 16);
  s1lo += __shfl_xor(s1lo, 32); s1hi += __shfl_xor(s1hi, 32);
  s2lo += __shfl_xor(s2lo, 32); s2hi += __shfl_xor(s2hi, 32);
  if ((tid & 63) < 16) {
    atomicAdd(&sstat[e2], s1lo);
    atomicAdd(&sstat[e2 + 16], s1hi);
    atomicAdd(&sstat[cENC + e2], s2lo);
    atomicAdd(&sstat[cENC + e2 + 16], s2hi);
  }
  __syncthreads();
  if (tid < 2 * cENC) atomicAdd(&statsEnc[tid], sstat[tid]);
}

// ---------------- CSR build ----------------
__global__ void k_hist(const int* __restrict__ dst, int nE, int* __restrict__ cnt) {
  int e = blockIdx.x * 256 + threadIdx.x;
  if (e < nE) atomicAdd(&cnt[dst[e]], 1);
}

__global__ void k_scan_local(const int* __restrict__ deg, int n,
                             int* __restrict__ out, int* __restrict__ partial) {
  int tid = threadIdx.x;
  int base = blockIdx.x * SC_ELEM + tid * 4;
  int4 v = make_int4(0, 0, 0, 0);
  if (base + 3 < n) v = *(const int4*)(deg + base);
  else { int* pv = (int*)&v; for (int k = 0; k < 4; ++k) if (base + k < n) pv[k] = deg[base + k]; }
  int tsum = v.x + v.y + v.z + v.w;
  int lane = tid & 63;
  int inc = tsum;
  #pragma unroll
  for (int o = 1; o < 64; o <<= 1) { int t = __shfl_up(inc, o); if (lane >= o) inc += t; }
  __shared__ int wtot[4];
  if (lane == 63) wtot[tid >> 6] = inc;
  __syncthreads();
  int w = tid >> 6, wbase = 0;
  #pragma unroll
  for (int k = 0; k < 3; ++k) if (k < w) wbase += wtot[k];
  int ebase = wbase + inc - tsum;
  int4 o4;
  o4.x = ebase; o4.y = ebase + v.x; o4.z = o4.y + v.y; o4.w = o4.z + v.z;
  if (base + 3 < n) *(int4*)(out + base) = o4;
  else { int* po = (int*)&o4; for (int k = 0; k < 4; ++k) if (base + k < n) out[base + k] = po[k]; }
  if (tid == 255) partial[blockIdx.x] = wbase + inc;
}

__global__ void k_scan_top(int* __restrict__ partial, int nb, int* __restrict__ total_out) {
  __shared__ int sd[256];
  int tid = threadIdx.x;
  int v = (tid < nb) ? partial[tid] : 0;
  sd[tid] = v;
  __syncthreads();
  for (int off = 1; off < 256; off <<= 1) {
    int t = (tid >= off) ? sd[tid - off] : 0;
    __syncthreads();
    sd[tid] += t;
    __syncthreads();
  }
  if (tid < nb) partial[tid] = sd[tid] - v;
  if (tid == 255) *total_out = sd[255];
}

__global__ void k_scan_add(int* __restrict__ rowptr, const int* __restrict__ partial,
                           int n, int* __restrict__ cursor) {
  int base = blockIdx.x * SC_ELEM + threadIdx.x * 4;
  int add = partial[blockIdx.x];
  if (base + 3 < n) {
    int4 v = *(int4*)(rowptr + base);
    v.x += add; v.y += add; v.z += add; v.w += add;
    *(int4*)(rowptr + base) = v;
    *(int4*)(cursor + base) = v;
  } else {
    for (int k = 0; k < 4; ++k)
      if (base + k < n) { int t = rowptr[base + k] + add; rowptr[base + k] = t; cursor[base + k] = t; }
  }
}

__global__ void k_scatter(const int* __restrict__ src, const int* __restrict__ dst, int nE,
                          int* __restrict__ cursor, int* __restrict__ out) {
  int e = blockIdx.x * 256 + threadIdx.x;
  if (e < nE) {
    int pos = atomicAdd(&cursor[dst[e]], 1);
    out[pos] = src[e];
  }
}

// ---------------- degree-based counting sort (for k_edge divergence) ----------------
__global__ void k_deg_hist(const int* __restrict__ rp, int n, int* __restrict__ bins) {
  int i = blockIdx.x * 256 + threadIdx.x;
  if (i < n) {
    int d = rp[i + 1] - rp[i];
    if (d > 63) d = 63;
    atomicAdd(&bins[d], 1);
  }
}
__global__ void k_deg_scan(int* __restrict__ bins) {   // 1 block, 64 threads
  int tid = threadIdx.x;
  int v = bins[tid];
  int inc = v;
  #pragma unroll
  for (int o = 1; o < 64; o <<= 1) { int t = __shfl_up(inc, o); if (tid >= o) inc += t; }
  bins[tid] = inc - v;     // exclusive offsets (cursor)
}
__global__ void k_deg_scatter(const int* __restrict__ rp, int n,
                              int* __restrict__ bins, int* __restrict__ perm) {
  int i = blockIdx.x * 256 + threadIdx.x;
  if (i < n) {
    int d = rp[i + 1] - rp[i];
    if (d > 63) d = 63;
    int pos = atomicAdd(&bins[d], 1);
    perm[pos] = i;
  }
}

// ---------------- l2h gather via CSR (2-way unrolled) ----------------
__global__ void k_gather_csr(const float* __restrict__ enc, const int* __restrict__ rowptr,
                             const int* __restrict__ srcs, const float* __restrict__ statsEnc,
                             const float* __restrict__ g, const float* __restrict__ bb,
                             float* __restrict__ agg) {
  __shared__ float ssc[cENC], ssh[cENC];
  int tid = threadIdx.x;
  if (tid < cENC) {
    float m = statsEnc[tid] * INV_NLOW;
    float var = statsEnc[cENC + tid] * INV_NLOW - m * m;
    float sc = g[tid] * rsqrtf(var + cEPS);
    ssc[tid] = sc;
    ssh[tid] = bb[tid] - m * sc;
  }
  __syncthreads();
  int c = tid & 31;
  int n = blockIdx.x * 8 + (tid >> 5);
  int lo = rowptr[n], hi = rowptr[n + 1];
  float sum = 0.0f;
  int i = lo;
  for (; i + 1 < hi; i += 2) {
    int s0 = srcs[i], s1 = srcs[i + 1];
    sum += enc[(size_t)s0 * cENC + c] + enc[(size_t)s1 * cENC + c];
  }
  if (i < hi) sum += enc[(size_t)srcs[i] * cENC + c];
  float deg = (float)(hi - lo);
  agg[(size_t)n * cENC + c] = (ssc[c] * sum + deg * ssh[c]) / fmaxf(deg, 1.0f);
}

// ---------------- down-projection + BN0 stats ----------------
__global__ void k_down(const float* __restrict__ agg,
                       const float* __restrict__ z_std, const float* __restrict__ land,
                       const float* __restrict__ Wrel, const float* __restrict__ brel,
                       const float* __restrict__ Wroot,
                       float* __restrict__ x0, float* __restrict__ stats) {
  __shared__ float sstat[2 * cD];
  __shared__ float sWrel[cD * cENC], sWroot[cD * cHIGH_IN], sbrel[cD];
  int tid = threadIdx.x;
  if (tid < 2 * cD) sstat[tid] = 0.0f;
  for (int i = tid; i < cD * cENC; i += 256) sWrel[i] = Wrel[i];
  if (tid < cD * cHIGH_IN) sWroot[tid] = Wroot[tid];
  if (tid < cD) sbrel[tid] = brel[tid];
  __syncthreads();

  int n = blockIdx.x * 256 + tid;
  bool valid = n < cN_HIGH;
  float a[cENC], zz[cHIGH_IN];
  if (valid) {
    const float4* ar4 = (const float4*)(agg + (size_t)n * cENC);
    #pragma unroll
    for (int k = 0; k < cENC / 4; ++k) {
      float4 t4 = ar4[k];
      a[4*k] = t4.x; a[4*k+1] = t4.y; a[4*k+2] = t4.z; a[4*k+3] = t4.w;
    }
    #pragma unroll
    for (int k = 0; k < 6; ++k) zz[k] = z_std[(size_t)n * 6 + k];
    zz[6] = land[n];
  } else {
    #pragma unroll
    for (int k = 0; k < cENC; ++k) a[k] = 0.0f;
    #pragma unroll
    for (int k = 0; k < cHIGH_IN; ++k) zz[k] = 0.0f;
  }
  int lane = tid & 63;
  #pragma unroll
  for (int d = 0; d < cD; ++d) {
    float acc = sbrel[d];
    #pragma unroll
    for (int k = 0; k < cENC; ++k) acc += a[k] * sWrel[d * cENC + k];
    #pragma unroll
    for (int k = 0; k < cHIGH_IN; ++k) acc += zz[k] * sWroot[d * cHIGH_IN + k];
    if (valid) x0[(size_t)n * cD + d] = acc;
    float v = valid ? acc : 0.0f;
    float s1 = v, s2 = v * v;
    #pragma unroll
    for (int o = 32; o > 0; o >>= 1) { s1 += __shfl_down(s1, o); s2 += __shfl_down(s2, o); }
    if (lane == 0) { atomicAdd(&sstat[d], s1); atomicAdd(&sstat[cD + d], s2); }
  }
  __syncthreads();
  if (tid < 2 * cD) atomicAdd(&stats[tid], sstat[tid]);
}

// ---------------- GAT node transform (also emits bf16 xl rows) ----------------
__global__ void k_transform(const float* __restrict__ xin, const float* __restrict__ stats,
                            const float* __restrict__ g, const float* __restrict__ b,
                            const float* __restrict__ Wl, const float* __restrict__ bl,
                            const float* __restrict__ Wr, const float* __restrict__ br,
                            int applyRelu,
                            float* __restrict__ xl, float* __restrict__ xr,
                            unsigned short* __restrict__ xlb) {
  __shared__ float ssc[cD], ssh[cD], sWl[cD * cD], sWr[cD * cD], sbl[cD], sbr[cD];
  int tid = threadIdx.x;
  if (tid < cD) {
    float m = stats[tid] * INV_NHIGH;
    float v = stats[cD + tid] * INV_NHIGH - m * m;
    float sc = g[tid] * rsqrtf(v + cEPS);
    ssc[tid] = sc;
    ssh[tid] = b[tid] - m * sc;
    sbl[tid] = bl[tid];
    sbr[tid] = br[tid];
  }
  if (tid < cD * cD) { sWl[tid] = Wl[tid]; sWr[tid] = Wr[tid]; }
  __syncthreads();

  int n = blockIdx.x * 256 + tid;
  if (n >= cN_HIGH) return;
  float act[cD];
  const float* xp = xin + (size_t)n * cD;
  #pragma unroll
  for (int d = 0; d < cD; ++d) {
    float v = xp[d] * ssc[d] + ssh[d];
    if (applyRelu) v = fmaxf(v, 0.0f);
    act[d] = v;
  }
  float alv[cD];
  float* xlp = xl + (size_t)n * cD;
  float* xrp = xr + (size_t)n * cD;
  #pragma unroll
  for (int d = 0; d < cD; ++d) {
    float al = sbl[d], ar = sbr[d];
    #pragma unroll
    for (int k = 0; k < cD; ++k) { al += act[k] * sWl[d * cD + k]; ar += act[k] * sWr[d * cD + k]; }
    alv[d] = al;
    xlp[d] = al;
    xrp[d] = ar;
  }
  uint4 w0, w1;
  unsigned int* pw = (unsigned int*)&w0;
  #pragma unroll
  for (int k = 0; k < 4; ++k)
    pw[k] = f32_to_bf16_bits(alv[2 * k]) | (f32_to_bf16_bits(alv[2 * k + 1]) << 16);
  unsigned int* pw1 = (unsigned int*)&w1;
  #pragma unroll
  for (int k = 0; k < 4; ++k)
    pw1[k] = f32_to_bf16_bits(alv[8 + 2 * k]) | (f32_to_bf16_bits(alv[8 + 2 * k + 1]) << 16);
  uint4* dst = (uint4*)(xlb + (size_t)n * cD);
  dst[0] = w0;
  dst[1] = w1;
}

// ---------------- fused GAT edge pass: degree-sorted nodes, 8 lanes/node ----------------
template<int FINAL>
__global__ __launch_bounds__(256)
void k_edge(const float* __restrict__ xl, const float* __restrict__ xr,
            const unsigned short* __restrict__ xlb, const int* __restrict__ perm,
            const int* __restrict__ rowptr, const int* __restrict__ srcs,
            const float* __restrict__ att, const float* __restrict__ bias,
            const float* __restrict__ pW, const float* __restrict__ pb,
            float* __restrict__ xout, float* __restrict__ stats,
            float* __restrict__ out) {
  __shared__ float satt[cD], sbias[cD], spw[cD];
  __shared__ float sstat[2 * cD];
  int tid = threadIdx.x;
  if (tid < cD) { satt[tid] = att[tid]; sbias[tid] = bias[tid]; spw[tid] = FINAL ? pW[tid] : 0.0f; }
  if (!FINAL && tid < 2 * cD) sstat[tid] = 0.0f;
  __syncthreads();

  int d2  = tid & 7;            // channel-pair index
  int idx = blockIdx.x * 32 + (tid >> 3);
  bool valid = idx < cN_HIGH;
  int n = valid ? perm[idx] : 0;   // degree-sorted: all 8 groups in a wave have ~equal degree

  float a0 = satt[2 * d2], a1 = satt[2 * d2 + 1];
  float xr0 = 0.0f, xr1 = 0.0f, xs0 = 0.0f, xs1 = 0.0f;
  int lo = 0, hi = 0;
  if (valid) {
    float2 t2 = *(const float2*)(xr + (size_t)n * cD + 2 * d2);
    xr0 = t2.x; xr1 = t2.y;
    float2 t3 = *(const float2*)(xl + (size_t)n * cD + 2 * d2);
    xs0 = t3.x; xs1 = t3.y;
    lo = rowptr[n]; hi = rowptr[n + 1];
  }

  float w0 = xs0 + xr0; w0 = w0 > 0.0f ? w0 : cSLOPE * w0;
  float w1 = xs1 + xr1; w1 = w1 > 0.0f ? w1 : cSLOPE * w1;
  float pq = w0 * a0 + w1 * a1;
  pq += __shfl_xor(pq, 1); pq += __shfl_xor(pq, 2); pq += __shfl_xor(pq, 4);
  float ex = __expf(pq);
  float denom = ex;
  float num0 = ex * xs0, num1 = ex * xs1;

  const unsigned int* xlw = (const unsigned int*)xlb;
  int i = lo;
  for (; i + 3 < hi; i += 4) {
    int s0 = srcs[i], s1 = srcs[i + 1], s2 = srcs[i + 2], s3 = srcs[i + 3];
    unsigned int v0 = xlw[(size_t)s0 * 8 + d2];
    unsigned int v1 = xlw[(size_t)s1 * 8 + d2];
    unsigned int v2 = xlw[(size_t)s2 * 8 + d2];
    unsigned int v3 = xlw[(size_t)s3 * 8 + d2];
    float x00 = __uint_as_float(v0 << 16), x01 = __uint_as_float(v0 & 0xFFFF0000u);
    float x10 = __uint_as_float(v1 << 16), x11 = __uint_as_float(v1 & 0xFFFF0000u);
    float x20 = __uint_as_float(v2 << 16), x21 = __uint_as_float(v2 & 0xFFFF0000u);
    float x30 = __uint_as_float(v3 << 16), x31 = __uint_as_float(v3 & 0xFFFF0000u);
    float u00 = x00 + xr0; u00 = u00 > 0.0f ? u00 : cSLOPE * u00;
    float u01 = x01 + xr1; u01 = u01 > 0.0f ? u01 : cSLOPE * u01;
    float u10 = x10 + xr0; u10 = u10 > 0.0f ? u10 : cSLOPE * u10;
    float u11 = x11 + xr1; u11 = u11 > 0.0f ? u11 : cSLOPE * u11;
    float u20 = x20 + xr0; u20 = u20 > 0.0f ? u20 : cSLOPE * u20;
    float u21 = x21 + xr1; u21 = u21 > 0.0f ? u21 : cSLOPE * u21;
    float u30 = x30 + xr0; u30 = u30 > 0.0f ? u30 : cSLOPE * u30;
    float u31 = x31 + xr1; u31 = u31 > 0.0f ? u31 : cSLOPE * u31;
    float q0 = u00 * a0 + u01 * a1;
    float q1 = u10 * a0 + u11 * a1;
    float q2 = u20 * a0 + u21 * a1;
    float q3 = u30 * a0 + u31 * a1;
    q0 += __shfl_xor(q0, 1); q1 += __shfl_xor(q1, 1); q2 += __shfl_xor(q2, 1); q3 += __shfl_xor(q3, 1);
    q0 += __shfl_xor(q0, 2); q1 += __shfl_xor(q1, 2); q2 += __shfl_xor(q2, 2); q3 += __shfl_xor(q3, 2);
    q0 += __shfl_xor(q0, 4); q1 += __shfl_xor(q1, 4); q2 += __shfl_xor(q2, 4); q3 += __shfl_xor(q3, 4);
    float e0 = __expf(q0), e1 = __expf(q1), e2c = __expf(q2), e3 = __expf(q3);
    denom += (e0 + e1) + (e2c + e3);
    num0 += e0 * x00 + e1 * x10 + e2c * x20 + e3 * x30;
    num1 += e0 * x01 + e1 * x11 + e2c * x21 + e3 * x31;
  }
  for (; i < hi; ++i) {
    int s = srcs[i];
    unsigned int v = xlw[(size_t)s * 8 + d2];
    float x0 = __uint_as_float(v << 16), x1 = __uint_as_float(v & 0xFFFF0000u);
    float u0 = x0 + xr0; u0 = u0 > 0.0f ? u0 : cSLOPE * u0;
    float u1 = x1 + xr1; u1 = u1 > 0.0f ? u1 : cSLOPE * u1;
    float q = u0 * a0 + u1 * a1;
    q += __shfl_xor(q, 1); q += __shfl_xor(q, 2); q += __shfl_xor(q, 4);
    float e = __expf(q);
    denom += e;
    num0 += e * x0;
    num1 += e * x1;
  }
  float cnt = (float)(hi - lo + 1);
  float inv = __builtin_amdgcn_rcpf(denom * cnt);
  float res0 = num0 * inv + sbias[2 * d2];
  float res1 = num1 * inv + sbias[2 * d2 + 1];

  if (FINAL) {
    float t = fmaxf(res0, 0.0f) * spw[2 * d2] + fmaxf(res1, 0.0f) * spw[2 * d2 + 1];
    t += __shfl_xor(t, 1); t += __shfl_xor(t, 2); t += __shfl_xor(t, 4);
    if (valid && d2 == 0) out[n] = t + pb[0];
  } else {
    if (!valid) { res0 = 0.0f; res1 = 0.0f; }
    else *(float2*)(xout + (size_t)n * cD + 2 * d2) = make_float2(res0, res1);
    float s10 = res0, s11 = res1, s20 = res0 * res0, s21 = res1 * res1;
    s10 += __shfl_xor(s10, 8);  s11 += __shfl_xor(s11, 8);  s20 += __shfl_xor(s20, 8);  s21 += __shfl_xor(s21, 8);
    s10 += __shfl_xor(s10, 16); s11 += __shfl_xor(s11, 16); s20 += __shfl_xor(s20, 16); s21 += __shfl_xor(s21, 16);
    s10 += __shfl_xor(s10, 32); s11 += __shfl_xor(s11, 32); s20 += __shfl_xor(s20, 32); s21 += __shfl_xor(s21, 32);
    if ((tid & 63) < 8) {
      atomicAdd(&sstat[2 * d2], s10);
      atomicAdd(&sstat[2 * d2 + 1], s11);
      atomicAdd(&sstat[cD + 2 * d2], s20);
      atomicAdd(&sstat[cD + 2 * d2 + 1], s21);
    }
    __syncthreads();
    if (tid < 2 * cD) atomicAdd(&stats[tid], sstat[tid]);
  }
}

// ---------------- launch ----------------
extern "C" void kernel_launch(void* const* d_in, const int* in_sizes, int n_in,
                              void* d_out, int out_size, void* d_ws, size_t ws_size,
                              hipStream_t stream) {
  const float* x_low    = (const float*)d_in[0];
  const float* z_std    = (const float*)d_in[1];
  const float* land     = (const float*)d_in[2];
  const int*   l2h_src  = (const int*)d_in[3];
  const int*   l2h_dst  = (const int*)d_in[4];
  const int*   hh_src   = (const int*)d_in[5];
  const int*   hh_dst   = (const int*)d_in[6];
  const float* gWih     = (const float*)d_in[7];
  const float* gWhh     = (const float*)d_in[8];
  const float* gbih     = (const float*)d_in[9];
  const float* gbhh     = (const float*)d_in[10];
  const float* dW       = (const float*)d_in[11];
  const float* db       = (const float*)d_in[12];
  const float* bn_enc_g = (const float*)d_in[13];
  const float* bn_enc_b = (const float*)d_in[14];
  const float* Wrel     = (const float*)d_in[15];
  const float* brel     = (const float*)d_in[16];
  const float* Wroot    = (const float*)d_in[17];
  const float* gat_Wl   = (const float*)d_in[18];
  const float* gat_bl   = (const float*)d_in[19];
  const float* gat_Wr   = (const float*)d_in[20];
  const float* gat_br   = (const float*)d_in[21];
  const float* gat_att  = (const float*)d_in[22];
  const float* gat_bias = (const float*)d_in[23];
  const float* bn_g     = (const float*)d_in[24];
  const float* bn_b     = (const float*)d_in[25];
  const float* pred_W   = (const float*)d_in[26];
  const float* pred_b   = (const float*)d_in[27];

  float* ws = (float*)d_ws;
  float* hs   = ws + OFF_HS;
  float* agg  = ws + OFF_AGG;
  float* enc  = ws + OFF_ENC;
  float* xA   = ws + OFF_XA;
  float* xB   = ws + OFF_XB;
  float* xl   = ws + OFF_XL;
  float* xr   = ws + OFF_XR;
  float* statsEnc = ws + OFF_STAT;
  float* statsX   = ws + OFF_STAT + 64;
  int* rp_hh  = (int*)(ws + OFF_RPH);
  int* src_hh = (int*)(ws + OFF_SRH);
  int* rp_l2h = (int*)(ws + OFF_RPL);
  int* src_l2h= (int*)(ws + OFF_SRL);
  int* cursor = (int*)(ws + OFF_CUR);
  int* part   = (int*)(ws + OFF_PART);
  unsigned short* xlb = (unsigned short*)(ws + OFF_XLB);
  int* perm   = (int*)(ws + OFF_PERM);
  int* bins   = (int*)(ws + OFF_BINS);

  hipMemsetAsync(statsEnc, 0, 256 * sizeof(float), stream);
  const int NODE_GRID = (cN_HIGH + 255) / 256;

  // --- CSR build: hh ---
  hipMemsetAsync(cursor, 0, cN_HIGH * sizeof(int), stream);
  k_hist<<<(cE_HH + 255) / 256, 256, 0, stream>>>(hh_dst, cE_HH, cursor);
  k_scan_local<<<SC_NB, 256, 0, stream>>>(cursor, cN_HIGH, rp_hh, part);
  k_scan_top<<<1, 256, 0, stream>>>(part, SC_NB, rp_hh + cN_HIGH);
  k_scan_add<<<SC_NB, 256, 0, stream>>>(rp_hh, part, cN_HIGH, cursor);
  k_scatter<<<(cE_HH + 255) / 256, 256, 0, stream>>>(hh_src, hh_dst, cE_HH, cursor, src_hh);
  // --- degree sort of high-res nodes (kills k_edge wave divergence) ---
  hipMemsetAsync(bins, 0, 64 * sizeof(int), stream);
  k_deg_hist<<<NODE_GRID, 256, 0, stream>>>(rp_hh, cN_HIGH, bins);
  k_deg_scan<<<1, 64, 0, stream>>>(bins);
  k_deg_scatter<<<NODE_GRID, 256, 0, stream>>>(rp_hh, cN_HIGH, bins, perm);
  // --- CSR build: l2h ---
  hipMemsetAsync(cursor, 0, cN_HIGH * sizeof(int), stream);
  k_hist<<<(cE_L2H + 255) / 256, 256, 0, stream>>>(l2h_dst, cE_L2H, cursor);
  k_scan_local<<<SC_NB, 256, 0, stream>>>(cursor, cN_HIGH, rp_l2h, part);
  k_scan_top<<<1, 256, 0, stream>>>(part, SC_NB, rp_l2h + cN_HIGH);
  k_scan_add<<<SC_NB, 256, 0, stream>>>(rp_l2h, part, cN_HIGH, cursor);
  k_scatter<<<(cE_L2H + 255) / 256, 256, 0, stream>>>(l2h_src, l2h_dst, cE_L2H, cursor, src_l2h);

  // --- encoder ---
  k_gru<<<cN_LOW / GN, GB, 0, stream>>>(x_low, gWih, gWhh, gbih, gbhh, hs);
  k_dense<<<cN_LOW / cDN, 256, 0, stream>>>(hs, dW, db, enc, statsEnc);
  k_gather_csr<<<cN_HIGH / 8, 256, 0, stream>>>(enc, rp_l2h, src_l2h, statsEnc,
                                                bn_enc_g, bn_enc_b, agg);
  k_down<<<NODE_GRID, 256, 0, stream>>>(agg, z_std, land, Wrel, brel, Wroot, xA, statsX);

  const int EDGE_GRID = (cN_HIGH + 31) / 32;
  // --- 5 GATv2 layers ---
  for (int i = 0; i < cNL; ++i) {
    float* xin  = (i & 1) ? xB : xA;
    float* xout = (i & 1) ? xA : xB;
    k_transform<<<NODE_GRID, 256, 0, stream>>>(xin, statsX + 32 * i,
                                               bn_g + 16 * i, bn_b + 16 * i,
                                               gat_Wl + 256 * i, gat_bl + 16 * i,
                                               gat_Wr + 256 * i, gat_br + 16 * i,
                                               (i > 0) ? 1 : 0, xl, xr, xlb);
    if (i < cNL - 1) {
      k_edge<0><<<EDGE_GRID, 256, 0, stream>>>(xl, xr, xlb, perm, rp_hh, src_hh,
                                               gat_att + 16 * i, gat_bias + 16 * i,
                                               nullptr, nullptr,
                                               xout, statsX + 32 * (i + 1), nullptr);
    } else {
      k_edge<1><<<EDGE_GRID, 256, 0, stream>>>(xl, xr, xlb, perm, rp_hh, src_hh,
                                               gat_att + 16 * i, gat_bias + 16 * i,
                                               pred_W, pred_b,
                                               nullptr, nullptr, (float*)d_out);
    }
  }
}

// Round 12
// 952.208 us; speedup vs baseline: 1.9598x; 1.9598x over previous
//
#include <hip/hip_runtime.h>
#include <hip/hip_bf16.h>
#include <cstddef>

// ---------------- problem constants ----------------
constexpr int cN_LOW  = 20000;
constexpr int cN_HIGH = 150000;
constexpr int cSEQ = 25;
constexpr int cHIN = 25;
constexpr int cHHID = 25;
constexpr int cENC = 32;
constexpr int cHIGH_IN = 7;
constexpr int cD = 16;
constexpr int cNL = 5;
constexpr int cE_L2H = 1350000;
constexpr int cE_HH = 1200000;
constexpr float cEPS = 1e-5f;
constexpr float cSLOPE = 0.2f;
constexpr float INV_NLOW  = 1.0f / (float)cN_LOW;
constexpr float INV_NHIGH = 1.0f / (float)cN_HIGH;

constexpr int cHSP = 640;     // padded hs row stride: 10 exact 64-f chunks

// scan geometry
constexpr int SC_ELEM = 1024;
constexpr int SC_NB   = (cN_HIGH + SC_ELEM - 1) / SC_ELEM;     // 147
static_assert(SC_NB <= 256, "top scan assumes <=256 partials");

// ---------------- workspace layout (4-byte element offsets) ----------------
constexpr size_t OFF_HS   = 0;                                   // [N_LOW*640]
constexpr size_t SZ_HS    = (size_t)cN_LOW * cHSP;
constexpr size_t OFF_AGG  = 0;                                   // alias (hs dead after k_dense)
constexpr size_t OFF_ENC  = OFF_HS + SZ_HS;                      // [N_LOW*32]
constexpr size_t SZ_ENC   = (size_t)cN_LOW * cENC;
constexpr size_t OFF_XA   = OFF_ENC + SZ_ENC;
constexpr size_t OFF_XB   = OFF_XA + (size_t)cN_HIGH * cD;
constexpr size_t OFF_XL   = OFF_XB + (size_t)cN_HIGH * cD;
constexpr size_t OFF_XR   = OFF_XL + (size_t)cN_HIGH * cD;
constexpr size_t OFF_STAT = OFF_XR + (size_t)cN_HIGH * cD;       // [256]
constexpr size_t OFF_RPH  = OFF_STAT + 256;                      // rowptr_hh [N_HIGH+4]
constexpr size_t OFF_SRH  = OFF_RPH + cN_HIGH + 4;               // src_hh [E_HH]
constexpr size_t OFF_RPL  = OFF_SRH + cE_HH;                     // rowptr_l2h [N_HIGH+4]
constexpr size_t OFF_SRL  = OFF_RPL + cN_HIGH + 4;               // src_l2h [E_L2H]
constexpr size_t OFF_CUR  = OFF_SRL + cE_L2H;                    // cursor [N_HIGH]
constexpr size_t OFF_PART = OFF_CUR + cN_HIGH;                   // partials [256]
constexpr size_t OFF_XLB  = OFF_PART + 256;                      // xl bf16 [N_HIGH*16 ushort]

__device__ __forceinline__ float fast_sigmoid(float a) {
  return __builtin_amdgcn_rcpf(1.0f + __expf(-a));
}
__device__ __forceinline__ float fast_tanh(float a) {
  float t = __expf(-2.0f * a);
  return (1.0f - t) * __builtin_amdgcn_rcpf(1.0f + t);
}
__device__ __forceinline__ unsigned int f32_to_bf16_bits(float f) {
  unsigned int u = __float_as_uint(f);
  return (u + 0x7FFFu + ((u >> 16) & 1u)) >> 16;     // RNE
}
__device__ __forceinline__ void unpack8(uint4 v, float* x) {
  const unsigned int* w = (const unsigned int*)&v;
  #pragma unroll
  for (int m = 0; m < 4; ++m) {
    x[2 * m]     = __uint_as_float(w[m] << 16);
    x[2 * m + 1] = __uint_as_float(w[m] & 0xFFFF0000u);
  }
}

// ---------------- GRU kernel (gate-split, float4 broadcast vin reads) ----------------
constexpr int GN = 5;                 // nodes per block
constexpr int GB = GN * 50;           // 250 threads

__global__ __launch_bounds__(256, 4)
void k_gru(const float* __restrict__ x_low,
           const float* __restrict__ Wih, const float* __restrict__ Whh,
           const float* __restrict__ bih, const float* __restrict__ bhh,
           float* __restrict__ hs) {
  __shared__ __align__(16) float sx[2][GN][28];
  __shared__ __align__(16) float sh[2][GN][28];
  __shared__ float sgi[GN][76];
  __shared__ float sgh[GN][76];

  int tid = threadIdx.x;
  int nl  = tid / 50;
  int rem = tid % 50;
  int s   = rem / 25;          // 0: x-side, 1: h-side
  int j   = rem % 25;
  int n   = blockIdx.x * GN + nl;

  const float* Wb = (s == 0) ? Wih : Whh;
  const float* bb = (s == 0) ? bih : bhh;
  float w0[28], w1[28], w2[28];
  #pragma unroll
  for (int i = 0; i < 28; ++i) {
    w0[i] = (i < 25) ? Wb[j * 25 + i] : 0.0f;
    w1[i] = (i < 25) ? Wb[(25 + j) * 25 + i] : 0.0f;
    w2[i] = (i < 25) ? Wb[(50 + j) * 25 + i] : 0.0f;
  }
  float b0 = bb[j], b1 = bb[25 + j], b2 = bb[50 + j];

  const float* xrow = x_low + (size_t)n * 625;
  float* hrow = hs + (size_t)n * cHSP;
  if (s == 0 && j < 15) hrow[625 + j] = 0.0f;
  if (s == 0 && j < 3) {
    sx[0][nl][25 + j] = 0.0f; sx[1][nl][25 + j] = 0.0f;
    sh[0][nl][25 + j] = 0.0f; sh[1][nl][25 + j] = 0.0f;
  }
  if (s == 0) { sh[0][nl][j] = 0.0f; sx[0][nl][j] = xrow[j]; }
  __syncthreads();

  int p = 0, q = 0;
  for (int t = 0; t < cSEQ; ++t) {
    if (s == 0 && t + 1 < cSEQ) sx[q ^ 1][nl][j] = xrow[(t + 1) * 25 + j];
    const float4* vin4 = (const float4*)((s == 0) ? &sx[q][nl][0] : &sh[p][nl][0]);
    float g0 = b0, g1 = b1, g2 = b2;
    #pragma unroll
    for (int c = 0; c < 7; ++c) {
      float4 v = vin4[c];
      g0 += w0[4*c] * v.x + w0[4*c+1] * v.y + w0[4*c+2] * v.z + w0[4*c+3] * v.w;
      g1 += w1[4*c] * v.x + w1[4*c+1] * v.y + w1[4*c+2] * v.z + w1[4*c+3] * v.w;
      g2 += w2[4*c] * v.x + w2[4*c+1] * v.y + w2[4*c+2] * v.z + w2[4*c+3] * v.w;
    }
    float* gout = (s == 0) ? &sgi[nl][0] : &sgh[nl][0];
    gout[j] = g0; gout[25 + j] = g1; gout[50 + j] = g2;
    __syncthreads();
    if (s == 1) {
      float r  = fast_sigmoid(sgi[nl][j] + sgh[nl][j]);
      float z  = fast_sigmoid(sgi[nl][25 + j] + sgh[nl][25 + j]);
      float nn = fast_tanh(sgi[nl][50 + j] + r * sgh[nl][50 + j]);
      float hnew = (1.0f - z) * nn + z * sh[p][nl][j];
      sh[p ^ 1][nl][j] = hnew;
      hrow[t * 25 + j] = hnew;
    }
    p ^= 1; q ^= 1;
    __syncthreads();
  }
}

// ---------------- dense 625->32 + relu + BN stats (v4) ----------------
constexpr int cDN = 32;      // nodes per block
__global__ __launch_bounds__(256)
void k_dense(const float* __restrict__ hs, const float* __restrict__ W,
             const float* __restrict__ b, float* __restrict__ enc,
             float* __restrict__ statsEnc) {
  __shared__ __align__(16) float sW2[640 * 32];        // 80 KB: [f][e2-pair]
  __shared__ __align__(16) float sH[2][cDN * 68];      // 17.4 KB
  __shared__ float sstat[2 * cENC];
  int tid = threadIdx.x;
  for (int i = tid; i < 32 * 625; i += 256) {
    int e = i / 625, f = i % 625;
    sW2[f * 32 + (e & 15) * 2 + (e >> 4)] = W[i];
  }
  for (int i = tid; i < 32 * 15; i += 256)
    sW2[(625 + (i >> 5)) * 32 + (i & 31)] = 0.0f;
  if (tid < 2 * cENC) sstat[tid] = 0.0f;

  int e2 = tid & 15;
  int ng = (tid >> 4) & 3;
  int w  = tid >> 6;
  int rA = 8 * w + 2 * ng;
  int rB = rA + 1;
  size_t nbase = (size_t)blockIdx.x * cDN;

  int srow = tid >> 4;
  int sf4  = (tid & 15) * 4;
  const float* hsb = hs + nbase * cHSP;
  {
    float4 v0 = *(const float4*)(hsb + (size_t)srow * cHSP + sf4);
    float4 v1 = *(const float4*)(hsb + (size_t)(srow + 16) * cHSP + sf4);
    *(float4*)&sH[0][srow * 68 + sf4] = v0;
    *(float4*)&sH[0][(srow + 16) * 68 + sf4] = v1;
  }
  __syncthreads();

  float a00 = 0.0f, a01 = 0.0f, a10 = 0.0f, a11 = 0.0f;
  for (int c = 0; c < 10; ++c) {
    int buf = c & 1;
    if (c + 1 < 10) {
      const float* src = hsb + (c + 1) * 64;
      float4 v0 = *(const float4*)(src + (size_t)srow * cHSP + sf4);
      float4 v1 = *(const float4*)(src + (size_t)(srow + 16) * cHSP + sf4);
      *(float4*)&sH[buf ^ 1][srow * 68 + sf4] = v0;
      *(float4*)&sH[buf ^ 1][(srow + 16) * 68 + sf4] = v1;
    }
    const float* WC = sW2 + c * 64 * 32;
    #pragma unroll
    for (int fg = 0; fg < 16; ++fg) {
      float4 hA = *(const float4*)&sH[buf][rA * 68 + fg * 4];
      float4 hB = *(const float4*)&sH[buf][rB * 68 + fg * 4];
      const float* ha = (const float*)&hA;
      const float* hb = (const float*)&hB;
      #pragma unroll
      for (int k = 0; k < 4; ++k) {
        float2 wv = *(const float2*)&WC[(fg * 4 + k) * 32 + e2 * 2];
        a00 += wv.x * ha[k]; a01 += wv.y * ha[k];
        a10 += wv.x * hb[k]; a11 += wv.y * hb[k];
      }
    }
    __syncthreads();
  }
  float blo = b[e2], bhi = b[e2 + 16];
  float v00 = fmaxf(a00 + blo, 0.0f);
  float v01 = fmaxf(a01 + bhi, 0.0f);
  float v10 = fmaxf(a10 + blo, 0.0f);
  float v11 = fmaxf(a11 + bhi, 0.0f);
  size_t nA = nbase + rA, nB = nbase + rB;
  enc[nA * cENC + e2]      = v00;
  enc[nA * cENC + e2 + 16] = v01;
  enc[nB * cENC + e2]      = v10;
  enc[nB * cENC + e2 + 16] = v11;

  float s1lo = v00 + v10, s1hi = v01 + v11;
  float s2lo = v00 * v00 + v10 * v10, s2hi = v01 * v01 + v11 * v11;
  s1lo += __shfl_xor(s1lo, 16); s1hi += __shfl_xor(s1hi, 16);
  s2lo += __shfl_xor(s2lo, 16); s2hi += __shfl_xor(s2hi, 16);
  s1lo += __shfl_xor(s1lo, 32); s1hi += __shfl_xor(s1hi, 32);
  s2lo += __shfl_xor(s2lo, 32); s2hi += __shfl_xor(s2hi, 32);
  if ((tid & 63) < 16) {
    atomicAdd(&sstat[e2], s1lo);
    atomicAdd(&sstat[e2 + 16], s1hi);
    atomicAdd(&sstat[cENC + e2], s2lo);
    atomicAdd(&sstat[cENC + e2 + 16], s2hi);
  }
  __syncthreads();
  if (tid < 2 * cENC) atomicAdd(&statsEnc[tid], sstat[tid]);
}

// ---------------- CSR build ----------------
__global__ void k_hist(const int* __restrict__ dst, int nE, int* __restrict__ cnt) {
  int e = blockIdx.x * 256 + threadIdx.x;
  if (e < nE) atomicAdd(&cnt[dst[e]], 1);
}

__global__ void k_scan_local(const int* __restrict__ deg, int n,
                             int* __restrict__ out, int* __restrict__ partial) {
  int tid = threadIdx.x;
  int base = blockIdx.x * SC_ELEM + tid * 4;
  int4 v = make_int4(0, 0, 0, 0);
  if (base + 3 < n) v = *(const int4*)(deg + base);
  else { int* pv = (int*)&v; for (int k = 0; k < 4; ++k) if (base + k < n) pv[k] = deg[base + k]; }
  int tsum = v.x + v.y + v.z + v.w;
  int lane = tid & 63;
  int inc = tsum;
  #pragma unroll
  for (int o = 1; o < 64; o <<= 1) { int t = __shfl_up(inc, o); if (lane >= o) inc += t; }
  __shared__ int wtot[4];
  if (lane == 63) wtot[tid >> 6] = inc;
  __syncthreads();
  int w = tid >> 6, wbase = 0;
  #pragma unroll
  for (int k = 0; k < 3; ++k) if (k < w) wbase += wtot[k];
  int ebase = wbase + inc - tsum;
  int4 o4;
  o4.x = ebase; o4.y = ebase + v.x; o4.z = o4.y + v.y; o4.w = o4.z + v.z;
  if (base + 3 < n) *(int4*)(out + base) = o4;
  else { int* po = (int*)&o4; for (int k = 0; k < 4; ++k) if (base + k < n) out[base + k] = po[k]; }
  if (tid == 255) partial[blockIdx.x] = wbase + inc;
}

__global__ void k_scan_top(int* __restrict__ partial, int nb, int* __restrict__ total_out) {
  __shared__ int sd[256];
  int tid = threadIdx.x;
  int v = (tid < nb) ? partial[tid] : 0;
  sd[tid] = v;
  __syncthreads();
  for (int off = 1; off < 256; off <<= 1) {
    int t = (tid >= off) ? sd[tid - off] : 0;
    __syncthreads();
    sd[tid] += t;
    __syncthreads();
  }
  if (tid < nb) partial[tid] = sd[tid] - v;
  if (tid == 255) *total_out = sd[255];
}

__global__ void k_scan_add(int* __restrict__ rowptr, const int* __restrict__ partial,
                           int n, int* __restrict__ cursor) {
  int base = blockIdx.x * SC_ELEM + threadIdx.x * 4;
  int add = partial[blockIdx.x];
  if (base + 3 < n) {
    int4 v = *(int4*)(rowptr + base);
    v.x += add; v.y += add; v.z += add; v.w += add;
    *(int4*)(rowptr + base) = v;
    *(int4*)(cursor + base) = v;
  } else {
    for (int k = 0; k < 4; ++k)
      if (base + k < n) { int t = rowptr[base + k] + add; rowptr[base + k] = t; cursor[base + k] = t; }
  }
}

__global__ void k_scatter(const int* __restrict__ src, const int* __restrict__ dst, int nE,
                          int* __restrict__ cursor, int* __restrict__ out) {
  int e = blockIdx.x * 256 + threadIdx.x;
  if (e < nE) {
    int pos = atomicAdd(&cursor[dst[e]], 1);
    out[pos] = src[e];
  }
}

// ---------------- l2h gather via CSR (2-way unrolled) ----------------
__global__ void k_gather_csr(const float* __restrict__ enc, const int* __restrict__ rowptr,
                             const int* __restrict__ srcs, const float* __restrict__ statsEnc,
                             const float* __restrict__ g, const float* __restrict__ bb,
                             float* __restrict__ agg) {
  __shared__ float ssc[cENC], ssh[cENC];
  int tid = threadIdx.x;
  if (tid < cENC) {
    float m = statsEnc[tid] * INV_NLOW;
    float var = statsEnc[cENC + tid] * INV_NLOW - m * m;
    float sc = g[tid] * rsqrtf(var + cEPS);
    ssc[tid] = sc;
    ssh[tid] = bb[tid] - m * sc;
  }
  __syncthreads();
  int c = tid & 31;
  int n = blockIdx.x * 8 + (tid >> 5);
  int lo = rowptr[n], hi = rowptr[n + 1];
  float sum = 0.0f;
  int i = lo;
  for (; i + 1 < hi; i += 2) {
    int s0 = srcs[i], s1 = srcs[i + 1];
    sum += enc[(size_t)s0 * cENC + c] + enc[(size_t)s1 * cENC + c];
  }
  if (i < hi) sum += enc[(size_t)srcs[i] * cENC + c];
  float deg = (float)(hi - lo);
  agg[(size_t)n * cENC + c] = (ssc[c] * sum + deg * ssh[c]) / fmaxf(deg, 1.0f);
}

// ---------------- down-projection + BN0 stats ----------------
__global__ void k_down(const float* __restrict__ agg,
                       const float* __restrict__ z_std, const float* __restrict__ land,
                       const float* __restrict__ Wrel, const float* __restrict__ brel,
                       const float* __restrict__ Wroot,
                       float* __restrict__ x0, float* __restrict__ stats) {
  __shared__ float sstat[2 * cD];
  __shared__ float sWrel[cD * cENC], sWroot[cD * cHIGH_IN], sbrel[cD];
  int tid = threadIdx.x;
  if (tid < 2 * cD) sstat[tid] = 0.0f;
  for (int i = tid; i < cD * cENC; i += 256) sWrel[i] = Wrel[i];
  if (tid < cD * cHIGH_IN) sWroot[tid] = Wroot[tid];
  if (tid < cD) sbrel[tid] = brel[tid];
  __syncthreads();

  int n = blockIdx.x * 256 + tid;
  bool valid = n < cN_HIGH;
  float a[cENC], zz[cHIGH_IN];
  if (valid) {
    const float4* ar4 = (const float4*)(agg + (size_t)n * cENC);
    #pragma unroll
    for (int k = 0; k < cENC / 4; ++k) {
      float4 t4 = ar4[k];
      a[4*k] = t4.x; a[4*k+1] = t4.y; a[4*k+2] = t4.z; a[4*k+3] = t4.w;
    }
    #pragma unroll
    for (int k = 0; k < 6; ++k) zz[k] = z_std[(size_t)n * 6 + k];
    zz[6] = land[n];
  } else {
    #pragma unroll
    for (int k = 0; k < cENC; ++k) a[k] = 0.0f;
    #pragma unroll
    for (int k = 0; k < cHIGH_IN; ++k) zz[k] = 0.0f;
  }
  int lane = tid & 63;
  #pragma unroll
  for (int d = 0; d < cD; ++d) {
    float acc = sbrel[d];
    #pragma unroll
    for (int k = 0; k < cENC; ++k) acc += a[k] * sWrel[d * cENC + k];
    #pragma unroll
    for (int k = 0; k < cHIGH_IN; ++k) acc += zz[k] * sWroot[d * cHIGH_IN + k];
    if (valid) x0[(size_t)n * cD + d] = acc;
    float v = valid ? acc : 0.0f;
    float s1 = v, s2 = v * v;
    #pragma unroll
    for (int o = 32; o > 0; o >>= 1) { s1 += __shfl_down(s1, o); s2 += __shfl_down(s2, o); }
    if (lane == 0) { atomicAdd(&sstat[d], s1); atomicAdd(&sstat[cD + d], s2); }
  }
  __syncthreads();
  if (tid < 2 * cD) atomicAdd(&stats[tid], sstat[tid]);
}

// ---------------- GAT node transform (also emits bf16 xl rows) ----------------
__global__ void k_transform(const float* __restrict__ xin, const float* __restrict__ stats,
                            const float* __restrict__ g, const float* __restrict__ b,
                            const float* __restrict__ Wl, const float* __restrict__ bl,
                            const float* __restrict__ Wr, const float* __restrict__ br,
                            int applyRelu,
                            float* __restrict__ xl, float* __restrict__ xr,
                            unsigned short* __restrict__ xlb) {
  __shared__ float ssc[cD], ssh[cD], sWl[cD * cD], sWr[cD * cD], sbl[cD], sbr[cD];
  int tid = threadIdx.x;
  if (tid < cD) {
    float m = stats[tid] * INV_NHIGH;
    float v = stats[cD + tid] * INV_NHIGH - m * m;
    float sc = g[tid] * rsqrtf(v + cEPS);
    ssc[tid] = sc;
    ssh[tid] = b[tid] - m * sc;
    sbl[tid] = bl[tid];
    sbr[tid] = br[tid];
  }
  if (tid < cD * cD) { sWl[tid] = Wl[tid]; sWr[tid] = Wr[tid]; }
  __syncthreads();

  int n = blockIdx.x * 256 + tid;
  if (n >= cN_HIGH) return;
  float act[cD];
  const float* xp = xin + (size_t)n * cD;
  #pragma unroll
  for (int d = 0; d < cD; ++d) {
    float v = xp[d] * ssc[d] + ssh[d];
    if (applyRelu) v = fmaxf(v, 0.0f);
    act[d] = v;
  }
  float alv[cD];
  float* xlp = xl + (size_t)n * cD;
  float* xrp = xr + (size_t)n * cD;
  #pragma unroll
  for (int d = 0; d < cD; ++d) {
    float al = sbl[d], ar = sbr[d];
    #pragma unroll
    for (int k = 0; k < cD; ++k) { al += act[k] * sWl[d * cD + k]; ar += act[k] * sWr[d * cD + k]; }
    alv[d] = al;
    xlp[d] = al;
    xrp[d] = ar;
  }
  uint4 w0, w1;
  unsigned int* pw = (unsigned int*)&w0;
  #pragma unroll
  for (int k = 0; k < 4; ++k)
    pw[k] = f32_to_bf16_bits(alv[2 * k]) | (f32_to_bf16_bits(alv[2 * k + 1]) << 16);
  unsigned int* pw1 = (unsigned int*)&w1;
  #pragma unroll
  for (int k = 0; k < 4; ++k)
    pw1[k] = f32_to_bf16_bits(alv[8 + 2 * k]) | (f32_to_bf16_bits(alv[8 + 2 * k + 1]) << 16);
  uint4* dst = (uint4*)(xlb + (size_t)n * cD);
  dst[0] = w0;
  dst[1] = w1;
}

// ---------------- fused GAT edge pass v3: 2 lanes/node, 8 ch/lane ----------------
// r11 lesson: k_edge is dependency-chain + ds-pipe bound, not divergence bound.
// This version: 1 uint4 bf16 load per edge per lane, ONE shfl_xor(1) per edge
// (was 3), split-partial fma chains, 2-edge unroll -> 4 independent chains.
template<int FINAL>
__global__ __launch_bounds__(256)
void k_edge(const float* __restrict__ xl, const float* __restrict__ xr,
            const unsigned short* __restrict__ xlb,
            const int* __restrict__ rowptr, const int* __restrict__ srcs,
            const float* __restrict__ att, const float* __restrict__ bias,
            const float* __restrict__ pW, const float* __restrict__ pb,
            float* __restrict__ xout, float* __restrict__ stats,
            float* __restrict__ out) {
  __shared__ float sstat[2 * cD];
  int tid = threadIdx.x;
  if (!FINAL) {
    if (tid < 2 * cD) sstat[tid] = 0.0f;
    __syncthreads();
  }

  int half = tid & 1;
  int n = (blockIdx.x * 256 + tid) >> 1;
  bool valid = n < cN_HIGH;
  int base = half * 8;

  float av[8];
  #pragma unroll
  for (int k = 0; k < 8; ++k) av[k] = att[base + k];

  float xrv[8], num[8];
  float denom = 1.0f;          // overwritten if valid; avoids 0-div for pad lanes
  int lo = 0, hi = 0;
  if (valid) {
    #pragma unroll
    for (int k = 0; k < 2; ++k) {
      float4 t = *(const float4*)(xr + (size_t)n * cD + base + 4 * k);
      xrv[4*k] = t.x; xrv[4*k+1] = t.y; xrv[4*k+2] = t.z; xrv[4*k+3] = t.w;
    }
    float xsv[8];
    #pragma unroll
    for (int k = 0; k < 2; ++k) {
      float4 t = *(const float4*)(xl + (size_t)n * cD + base + 4 * k);
      xsv[4*k] = t.x; xsv[4*k+1] = t.y; xsv[4*k+2] = t.z; xsv[4*k+3] = t.w;
    }
    float qa = 0.0f, qb = 0.0f;
    #pragma unroll
    for (int k = 0; k < 8; ++k) {
      float u = xsv[k] + xrv[k];
      u = fmaxf(u, cSLOPE * u);
      if (k & 1) qb += u * av[k]; else qa += u * av[k];
    }
    float qq = qa + qb;
    qq += __shfl_xor(qq, 1);
    float e = __expf(qq);
    denom = e;
    #pragma unroll
    for (int k = 0; k < 8; ++k) num[k] = e * xsv[k];
    lo = rowptr[n]; hi = rowptr[n + 1];
  } else {
    #pragma unroll
    for (int k = 0; k < 8; ++k) { num[k] = 0.0f; xrv[k] = 0.0f; }
  }

  const uint4* xl4 = (const uint4*)xlb;
  int i = lo;
  for (; i + 1 < hi; i += 2) {
    int s0 = srcs[i], s1 = srcs[i + 1];
    uint4 v0 = xl4[(size_t)s0 * 2 + half];
    uint4 v1 = xl4[(size_t)s1 * 2 + half];
    float x0[8], x1[8];
    unpack8(v0, x0);
    unpack8(v1, x1);
    float q0a = 0.0f, q0b = 0.0f, q1a = 0.0f, q1b = 0.0f;
    #pragma unroll
    for (int k = 0; k < 8; ++k) {
      float u0 = x0[k] + xrv[k]; u0 = fmaxf(u0, cSLOPE * u0);
      float u1 = x1[k] + xrv[k]; u1 = fmaxf(u1, cSLOPE * u1);
      if (k & 1) { q0b += u0 * av[k]; q1b += u1 * av[k]; }
      else       { q0a += u0 * av[k]; q1a += u1 * av[k]; }
    }
    float q0 = q0a + q0b, q1 = q1a + q1b;
    q0 += __shfl_xor(q0, 1);
    q1 += __shfl_xor(q1, 1);
    float e0 = __expf(q0), e1 = __expf(q1);
    denom += e0 + e1;
    #pragma unroll
    for (int k = 0; k < 8; ++k) num[k] += e0 * x0[k] + e1 * x1[k];
  }
  if (i < hi) {
    int s = srcs[i];
    uint4 v = xl4[(size_t)s * 2 + half];
    float x[8];
    unpack8(v, x);
    float qa = 0.0f, qb = 0.0f;
    #pragma unroll
    for (int k = 0; k < 8; ++k) {
      float u = x[k] + xrv[k]; u = fmaxf(u, cSLOPE * u);
      if (k & 1) qb += u * av[k]; else qa += u * av[k];
    }
    float qq = qa + qb;
    qq += __shfl_xor(qq, 1);
    float e = __expf(qq);
    denom += e;
    #pragma unroll
    for (int k = 0; k < 8; ++k) num[k] += e * x[k];
  }

  float cnt = (float)(hi - lo + 1);
  float inv = __builtin_amdgcn_rcpf(denom * cnt);
  float res[8];
  #pragma unroll
  for (int k = 0; k < 8; ++k)
    res[k] = valid ? (num[k] * inv + bias[base + k]) : 0.0f;

  if (FINAL) {
    float t = 0.0f;
    #pragma unroll
    for (int k = 0; k < 8; ++k) t += fmaxf(res[k], 0.0f) * pW[base + k];
    t += __shfl_xor(t, 1);
    if (valid && half == 0) out[n] = t + pb[0];
  } else {
    if (valid) {
      float4* op = (float4*)(xout + (size_t)n * cD + base);
      op[0] = make_float4(res[0], res[1], res[2], res[3]);
      op[1] = make_float4(res[4], res[5], res[6], res[7]);
    }
    // stats: butterfly over same-parity lanes (masks 2..32), then LDS atomics
    #pragma unroll
    for (int k = 0; k < 8; ++k) {
      float s1 = res[k], s2 = res[k] * res[k];
      #pragma unroll
      for (int m = 2; m < 64; m <<= 1) { s1 += __shfl_xor(s1, m); s2 += __shfl_xor(s2, m); }
      if ((tid & 63) < 2) {
        atomicAdd(&sstat[base + k], s1);
        atomicAdd(&sstat[cD + base + k], s2);
      }
    }
    __syncthreads();
    if (tid < 2 * cD) atomicAdd(&stats[tid], sstat[tid]);
  }
}

// ---------------- launch ----------------
extern "C" void kernel_launch(void* const* d_in, const int* in_sizes, int n_in,
                              void* d_out, int out_size, void* d_ws, size_t ws_size,
                              hipStream_t stream) {
  const float* x_low    = (const float*)d_in[0];
  const float* z_std    = (const float*)d_in[1];
  const float* land     = (const float*)d_in[2];
  const int*   l2h_src  = (const int*)d_in[3];
  const int*   l2h_dst  = (const int*)d_in[4];
  const int*   hh_src   = (const int*)d_in[5];
  const int*   hh_dst   = (const int*)d_in[6];
  const float* gWih     = (const float*)d_in[7];
  const float* gWhh     = (const float*)d_in[8];
  const float* gbih     = (const float*)d_in[9];
  const float* gbhh     = (const float*)d_in[10];
  const float* dW       = (const float*)d_in[11];
  const float* db       = (const float*)d_in[12];
  const float* bn_enc_g = (const float*)d_in[13];
  const float* bn_enc_b = (const float*)d_in[14];
  const float* Wrel     = (const float*)d_in[15];
  const float* brel     = (const float*)d_in[16];
  const float* Wroot    = (const float*)d_in[17];
  const float* gat_Wl   = (const float*)d_in[18];
  const float* gat_bl   = (const float*)d_in[19];
  const float* gat_Wr   = (const float*)d_in[20];
  const float* gat_br   = (const float*)d_in[21];
  const float* gat_att  = (const float*)d_in[22];
  const float* gat_bias = (const float*)d_in[23];
  const float* bn_g     = (const float*)d_in[24];
  const float* bn_b     = (const float*)d_in[25];
  const float* pred_W   = (const float*)d_in[26];
  const float* pred_b   = (const float*)d_in[27];

  float* ws = (float*)d_ws;
  float* hs   = ws + OFF_HS;
  float* agg  = ws + OFF_AGG;
  float* enc  = ws + OFF_ENC;
  float* xA   = ws + OFF_XA;
  float* xB   = ws + OFF_XB;
  float* xl   = ws + OFF_XL;
  float* xr   = ws + OFF_XR;
  float* statsEnc = ws + OFF_STAT;
  float* statsX   = ws + OFF_STAT + 64;
  int* rp_hh  = (int*)(ws + OFF_RPH);
  int* src_hh = (int*)(ws + OFF_SRH);
  int* rp_l2h = (int*)(ws + OFF_RPL);
  int* src_l2h= (int*)(ws + OFF_SRL);
  int* cursor = (int*)(ws + OFF_CUR);
  int* part   = (int*)(ws + OFF_PART);
  unsigned short* xlb = (unsigned short*)(ws + OFF_XLB);

  hipMemsetAsync(statsEnc, 0, 256 * sizeof(float), stream);
  const int NODE_GRID = (cN_HIGH + 255) / 256;

  // --- CSR build: hh ---
  hipMemsetAsync(cursor, 0, cN_HIGH * sizeof(int), stream);
  k_hist<<<(cE_HH + 255) / 256, 256, 0, stream>>>(hh_dst, cE_HH, cursor);
  k_scan_local<<<SC_NB, 256, 0, stream>>>(cursor, cN_HIGH, rp_hh, part);
  k_scan_top<<<1, 256, 0, stream>>>(part, SC_NB, rp_hh + cN_HIGH);
  k_scan_add<<<SC_NB, 256, 0, stream>>>(rp_hh, part, cN_HIGH, cursor);
  k_scatter<<<(cE_HH + 255) / 256, 256, 0, stream>>>(hh_src, hh_dst, cE_HH, cursor, src_hh);
  // --- CSR build: l2h ---
  hipMemsetAsync(cursor, 0, cN_HIGH * sizeof(int), stream);
  k_hist<<<(cE_L2H + 255) / 256, 256, 0, stream>>>(l2h_dst, cE_L2H, cursor);
  k_scan_local<<<SC_NB, 256, 0, stream>>>(cursor, cN_HIGH, rp_l2h, part);
  k_scan_top<<<1, 256, 0, stream>>>(part, SC_NB, rp_l2h + cN_HIGH);
  k_scan_add<<<SC_NB, 256, 0, stream>>>(rp_l2h, part, cN_HIGH, cursor);
  k_scatter<<<(cE_L2H + 255) / 256, 256, 0, stream>>>(l2h_src, l2h_dst, cE_L2H, cursor, src_l2h);

  // --- encoder ---
  k_gru<<<cN_LOW / GN, GB, 0, stream>>>(x_low, gWih, gWhh, gbih, gbhh, hs);
  k_dense<<<cN_LOW / cDN, 256, 0, stream>>>(hs, dW, db, enc, statsEnc);
  k_gather_csr<<<cN_HIGH / 8, 256, 0, stream>>>(enc, rp_l2h, src_l2h, statsEnc,
                                                bn_enc_g, bn_enc_b, agg);
  k_down<<<NODE_GRID, 256, 0, stream>>>(agg, z_std, land, Wrel, brel, Wroot, xA, statsX);

  const int EDGE_GRID = (2 * cN_HIGH + 255) / 256;
  // --- 5 GATv2 layers ---
  for (int i = 0; i < cNL; ++i) {
    float* xin  = (i & 1) ? xB : xA;
    float* xout = (i & 1) ? xA : xB;
    k_transform<<<NODE_GRID, 256, 0, stream>>>(xin, statsX + 32 * i,
                                               bn_g + 16 * i, bn_b + 16 * i,
                                               gat_Wl + 256 * i, gat_bl + 16 * i,
                                               gat_Wr + 256 * i, gat_br + 16 * i,
                                               (i > 0) ? 1 : 0, xl, xr, xlb);
    if (i < cNL - 1) {
      k_edge<0><<<EDGE_GRID, 256, 0, stream>>>(xl, xr, xlb, rp_hh, src_hh,
                                               gat_att + 16 * i, gat_bias + 16 * i,
                                               nullptr, nullptr,
                                               xout, statsX + 32 * (i + 1), nullptr);
    } else {
      k_edge<1><<<EDGE_GRID, 256, 0, stream>>>(xl, xr, xlb, rp_hh, src_hh,
                                               gat_att + 16 * i, gat_bias + 16 * i,
                                               pred_W, pred_b,
                                               nullptr, nullptr, (float*)d_out);
    }
  }
}

// Round 13
// 949.993 us; speedup vs baseline: 1.9644x; 1.0023x over previous
//
#include <hip/hip_runtime.h>
#include <hip/hip_bf16.h>
#include <cstddef>

// ---------------- problem constants ----------------
constexpr int cN_LOW  = 20000;
constexpr int cN_HIGH = 150000;
constexpr int cSEQ = 25;
constexpr int cHIN = 25;
constexpr int cHHID = 25;
constexpr int cENC = 32;
constexpr int cHIGH_IN = 7;
constexpr int cD = 16;
constexpr int cNL = 5;
constexpr int cE_L2H = 1350000;
constexpr int cE_HH = 1200000;
constexpr float cEPS = 1e-5f;
constexpr float cSLOPE = 0.2f;
constexpr float INV_NLOW  = 1.0f / (float)cN_LOW;
constexpr float INV_NHIGH = 1.0f / (float)cN_HIGH;

constexpr int cHSP = 640;     // padded hs row stride: 10 exact 64-f chunks

// scan geometry
constexpr int SC_ELEM = 1024;
constexpr int SC_NB   = (cN_HIGH + SC_ELEM - 1) / SC_ELEM;     // 147
static_assert(SC_NB <= 256, "top scan assumes <=256 partials");

// ---------------- workspace layout (4-byte element offsets) ----------------
constexpr size_t OFF_HS   = 0;                                   // [N_LOW*640]
constexpr size_t SZ_HS    = (size_t)cN_LOW * cHSP;
constexpr size_t OFF_AGG  = 0;                                   // alias (hs dead after k_dense)
constexpr size_t OFF_ENC  = OFF_HS + SZ_HS;                      // [N_LOW*32]
constexpr size_t SZ_ENC   = (size_t)cN_LOW * cENC;
constexpr size_t OFF_XA   = OFF_ENC + SZ_ENC;
constexpr size_t OFF_XB   = OFF_XA + (size_t)cN_HIGH * cD;
constexpr size_t OFF_XL   = OFF_XB + (size_t)cN_HIGH * cD;
constexpr size_t OFF_XR   = OFF_XL + (size_t)cN_HIGH * cD;
constexpr size_t OFF_STAT = OFF_XR + (size_t)cN_HIGH * cD;       // [256]
constexpr size_t OFF_RPH  = OFF_STAT + 256;                      // rowptr_hh [N_HIGH+4]
constexpr size_t OFF_SRH  = OFF_RPH + cN_HIGH + 4;               // src_hh [E_HH]
constexpr size_t OFF_RPL  = OFF_SRH + cE_HH;                     // rowptr_l2h [N_HIGH+4]
constexpr size_t OFF_SRL  = OFF_RPL + cN_HIGH + 4;               // src_l2h [E_L2H]
constexpr size_t OFF_CUR  = OFF_SRL + cE_L2H;                    // cursor [N_HIGH]
constexpr size_t OFF_PART = OFF_CUR + cN_HIGH;                   // partials [256]
constexpr size_t OFF_XLB  = OFF_PART + 256;                      // xl bf16 [N_HIGH*16 ushort]

__device__ __forceinline__ float fast_sigmoid(float a) {
  return __builtin_amdgcn_rcpf(1.0f + __expf(-a));
}
__device__ __forceinline__ float fast_tanh(float a) {
  float t = __expf(-2.0f * a);
  return (1.0f - t) * __builtin_amdgcn_rcpf(1.0f + t);
}
__device__ __forceinline__ unsigned int f32_to_bf16_bits(float f) {
  unsigned int u = __float_as_uint(f);
  return (u + 0x7FFFu + ((u >> 16) & 1u)) >> 16;     // RNE
}
__device__ __forceinline__ void unpack8(uint4 v, float* x) {
  const unsigned int* w = (const unsigned int*)&v;
  #pragma unroll
  for (int m = 0; m < 4; ++m) {
    x[2 * m]     = __uint_as_float(w[m] << 16);
    x[2 * m + 1] = __uint_as_float(w[m] & 0xFFFF0000u);
  }
}

// ---------------- GRU kernel (gate-split, float4 broadcast vin reads) ----------------
// r12 counters (VGPR=60, VALUBusy=72%): launch_bounds(256,4) capped the
// allocator at 64 VGPR, so the 84 weight floats were re-loaded every t.
// (256,2) gives the 128-VGPR budget they need; 8 waves/CU remain for the
// 2-barrier/t latency.
constexpr int GN = 5;                 // nodes per block
constexpr int GB = GN * 50;           // 250 threads

__global__ __launch_bounds__(256, 2)
void k_gru(const float* __restrict__ x_low,
           const float* __restrict__ Wih, const float* __restrict__ Whh,
           const float* __restrict__ bih, const float* __restrict__ bhh,
           float* __restrict__ hs) {
  __shared__ __align__(16) float sx[2][GN][28];
  __shared__ __align__(16) float sh[2][GN][28];
  __shared__ float sgi[GN][76];
  __shared__ float sgh[GN][76];

  int tid = threadIdx.x;
  int nl  = tid / 50;
  int rem = tid % 50;
  int s   = rem / 25;          // 0: x-side, 1: h-side
  int j   = rem % 25;
  int n   = blockIdx.x * GN + nl;

  const float* Wb = (s == 0) ? Wih : Whh;
  const float* bb = (s == 0) ? bih : bhh;
  float w0[28], w1[28], w2[28];
  #pragma unroll
  for (int i = 0; i < 28; ++i) {
    w0[i] = (i < 25) ? Wb[j * 25 + i] : 0.0f;
    w1[i] = (i < 25) ? Wb[(25 + j) * 25 + i] : 0.0f;
    w2[i] = (i < 25) ? Wb[(50 + j) * 25 + i] : 0.0f;
  }
  float b0 = bb[j], b1 = bb[25 + j], b2 = bb[50 + j];

  const float* xrow = x_low + (size_t)n * 625;
  float* hrow = hs + (size_t)n * cHSP;
  if (s == 0 && j < 15) hrow[625 + j] = 0.0f;
  if (s == 0 && j < 3) {
    sx[0][nl][25 + j] = 0.0f; sx[1][nl][25 + j] = 0.0f;
    sh[0][nl][25 + j] = 0.0f; sh[1][nl][25 + j] = 0.0f;
  }
  if (s == 0) { sh[0][nl][j] = 0.0f; sx[0][nl][j] = xrow[j]; }
  __syncthreads();

  int p = 0, q = 0;
  for (int t = 0; t < cSEQ; ++t) {
    if (s == 0 && t + 1 < cSEQ) sx[q ^ 1][nl][j] = xrow[(t + 1) * 25 + j];
    const float4* vin4 = (const float4*)((s == 0) ? &sx[q][nl][0] : &sh[p][nl][0]);
    float g0 = b0, g1 = b1, g2 = b2;
    #pragma unroll
    for (int c = 0; c < 7; ++c) {
      float4 v = vin4[c];
      g0 += w0[4*c] * v.x + w0[4*c+1] * v.y + w0[4*c+2] * v.z + w0[4*c+3] * v.w;
      g1 += w1[4*c] * v.x + w1[4*c+1] * v.y + w1[4*c+2] * v.z + w1[4*c+3] * v.w;
      g2 += w2[4*c] * v.x + w2[4*c+1] * v.y + w2[4*c+2] * v.z + w2[4*c+3] * v.w;
    }
    float* gout = (s == 0) ? &sgi[nl][0] : &sgh[nl][0];
    gout[j] = g0; gout[25 + j] = g1; gout[50 + j] = g2;
    __syncthreads();
    if (s == 1) {
      float r  = fast_sigmoid(sgi[nl][j] + sgh[nl][j]);
      float z  = fast_sigmoid(sgi[nl][25 + j] + sgh[nl][25 + j]);
      float nn = fast_tanh(sgi[nl][50 + j] + r * sgh[nl][50 + j]);
      float hnew = (1.0f - z) * nn + z * sh[p][nl][j];
      sh[p ^ 1][nl][j] = hnew;
      hrow[t * 25 + j] = hnew;
    }
    p ^= 1; q ^= 1;
    __syncthreads();
  }
}

// ---------------- dense 625->32 + relu + BN stats (v4) ----------------
constexpr int cDN = 32;      // nodes per block
__global__ __launch_bounds__(256)
void k_dense(const float* __restrict__ hs, const float* __restrict__ W,
             const float* __restrict__ b, float* __restrict__ enc,
             float* __restrict__ statsEnc) {
  __shared__ __align__(16) float sW2[640 * 32];        // 80 KB: [f][e2-pair]
  __shared__ __align__(16) float sH[2][cDN * 68];      // 17.4 KB
  __shared__ float sstat[2 * cENC];
  int tid = threadIdx.x;
  for (int i = tid; i < 32 * 625; i += 256) {
    int e = i / 625, f = i % 625;
    sW2[f * 32 + (e & 15) * 2 + (e >> 4)] = W[i];
  }
  for (int i = tid; i < 32 * 15; i += 256)
    sW2[(625 + (i >> 5)) * 32 + (i & 31)] = 0.0f;
  if (tid < 2 * cENC) sstat[tid] = 0.0f;

  int e2 = tid & 15;
  int ng = (tid >> 4) & 3;
  int w  = tid >> 6;
  int rA = 8 * w + 2 * ng;
  int rB = rA + 1;
  size_t nbase = (size_t)blockIdx.x * cDN;

  int srow = tid >> 4;
  int sf4  = (tid & 15) * 4;
  const float* hsb = hs + nbase * cHSP;
  {
    float4 v0 = *(const float4*)(hsb + (size_t)srow * cHSP + sf4);
    float4 v1 = *(const float4*)(hsb + (size_t)(srow + 16) * cHSP + sf4);
    *(float4*)&sH[0][srow * 68 + sf4] = v0;
    *(float4*)&sH[0][(srow + 16) * 68 + sf4] = v1;
  }
  __syncthreads();

  float a00 = 0.0f, a01 = 0.0f, a10 = 0.0f, a11 = 0.0f;
  for (int c = 0; c < 10; ++c) {
    int buf = c & 1;
    if (c + 1 < 10) {
      const float* src = hsb + (c + 1) * 64;
      float4 v0 = *(const float4*)(src + (size_t)srow * cHSP + sf4);
      float4 v1 = *(const float4*)(src + (size_t)(srow + 16) * cHSP + sf4);
      *(float4*)&sH[buf ^ 1][srow * 68 + sf4] = v0;
      *(float4*)&sH[buf ^ 1][(srow + 16) * 68 + sf4] = v1;
    }
    const float* WC = sW2 + c * 64 * 32;
    #pragma unroll
    for (int fg = 0; fg < 16; ++fg) {
      float4 hA = *(const float4*)&sH[buf][rA * 68 + fg * 4];
      float4 hB = *(const float4*)&sH[buf][rB * 68 + fg * 4];
      const float* ha = (const float*)&hA;
      const float* hb = (const float*)&hB;
      #pragma unroll
      for (int k = 0; k < 4; ++k) {
        float2 wv = *(const float2*)&WC[(fg * 4 + k) * 32 + e2 * 2];
        a00 += wv.x * ha[k]; a01 += wv.y * ha[k];
        a10 += wv.x * hb[k]; a11 += wv.y * hb[k];
      }
    }
    __syncthreads();
  }
  float blo = b[e2], bhi = b[e2 + 16];
  float v00 = fmaxf(a00 + blo, 0.0f);
  float v01 = fmaxf(a01 + bhi, 0.0f);
  float v10 = fmaxf(a10 + blo, 0.0f);
  float v11 = fmaxf(a11 + bhi, 0.0f);
  size_t nA = nbase + rA, nB = nbase + rB;
  enc[nA * cENC + e2]      = v00;
  enc[nA * cENC + e2 + 16] = v01;
  enc[nB * cENC + e2]      = v10;
  enc[nB * cENC + e2 + 16] = v11;

  float s1lo = v00 + v10, s1hi = v01 + v11;
  float s2lo = v00 * v00 + v10 * v10, s2hi = v01 * v01 + v11 * v11;
  s1lo += __shfl_xor(s1lo, 16); s1hi += __shfl_xor(s1hi, 16);
  s2lo += __shfl_xor(s2lo, 16); s2hi += __shfl_xor(s2hi, 16);
  s1lo += __shfl_xor(s1lo, 32); s1hi += __shfl_xor(s1hi, 32);
  s2lo += __shfl_xor(s2lo, 32); s2hi += __shfl_xor(s2hi, 32);
  if ((tid & 63) < 16) {
    atomicAdd(&sstat[e2], s1lo);
    atomicAdd(&sstat[e2 + 16], s1hi);
    atomicAdd(&sstat[cENC + e2], s2lo);
    atomicAdd(&sstat[cENC + e2 + 16], s2hi);
  }
  __syncthreads();
  if (tid < 2 * cENC) atomicAdd(&statsEnc[tid], sstat[tid]);
}

// ---------------- CSR build ----------------
__global__ void k_hist(const int* __restrict__ dst, int nE, int* __restrict__ cnt) {
  int e = blockIdx.x * 256 + threadIdx.x;
  if (e < nE) atomicAdd(&cnt[dst[e]], 1);
}

__global__ void k_scan_local(const int* __restrict__ deg, int n,
                             int* __restrict__ out, int* __restrict__ partial) {
  int tid = threadIdx.x;
  int base = blockIdx.x * SC_ELEM + tid * 4;
  int4 v = make_int4(0, 0, 0, 0);
  if (base + 3 < n) v = *(const int4*)(deg + base);
  else { int* pv = (int*)&v; for (int k = 0; k < 4; ++k) if (base + k < n) pv[k] = deg[base + k]; }
  int tsum = v.x + v.y + v.z + v.w;
  int lane = tid & 63;
  int inc = tsum;
  #pragma unroll
  for (int o = 1; o < 64; o <<= 1) { int t = __shfl_up(inc, o); if (lane >= o) inc += t; }
  __shared__ int wtot[4];
  if (lane == 63) wtot[tid >> 6] = inc;
  __syncthreads();
  int w = tid >> 6, wbase = 0;
  #pragma unroll
  for (int k = 0; k < 3; ++k) if (k < w) wbase += wtot[k];
  int ebase = wbase + inc - tsum;
  int4 o4;
  o4.x = ebase; o4.y = ebase + v.x; o4.z = o4.y + v.y; o4.w = o4.z + v.z;
  if (base + 3 < n) *(int4*)(out + base) = o4;
  else { int* po = (int*)&o4; for (int k = 0; k < 4; ++k) if (base + k < n) out[base + k] = po[k]; }
  if (tid == 255) partial[blockIdx.x] = wbase + inc;
}

__global__ void k_scan_top(int* __restrict__ partial, int nb, int* __restrict__ total_out) {
  __shared__ int sd[256];
  int tid = threadIdx.x;
  int v = (tid < nb) ? partial[tid] : 0;
  sd[tid] = v;
  __syncthreads();
  for (int off = 1; off < 256; off <<= 1) {
    int t = (tid >= off) ? sd[tid - off] : 0;
    __syncthreads();
    sd[tid] += t;
    __syncthreads();
  }
  if (tid < nb) partial[tid] = sd[tid] - v;
  if (tid == 255) *total_out = sd[255];
}

__global__ void k_scan_add(int* __restrict__ rowptr, const int* __restrict__ partial,
                           int n, int* __restrict__ cursor) {
  int base = blockIdx.x * SC_ELEM + threadIdx.x * 4;
  int add = partial[blockIdx.x];
  if (base + 3 < n) {
    int4 v = *(int4*)(rowptr + base);
    v.x += add; v.y += add; v.z += add; v.w += add;
    *(int4*)(rowptr + base) = v;
    *(int4*)(cursor + base) = v;
  } else {
    for (int k = 0; k < 4; ++k)
      if (base + k < n) { int t = rowptr[base + k] + add; rowptr[base + k] = t; cursor[base + k] = t; }
  }
}

__global__ void k_scatter(const int* __restrict__ src, const int* __restrict__ dst, int nE,
                          int* __restrict__ cursor, int* __restrict__ out) {
  int e = blockIdx.x * 256 + threadIdx.x;
  if (e < nE) {
    int pos = atomicAdd(&cursor[dst[e]], 1);
    out[pos] = src[e];
  }
}

// ---------------- l2h gather via CSR (2-way unrolled) ----------------
__global__ void k_gather_csr(const float* __restrict__ enc, const int* __restrict__ rowptr,
                             const int* __restrict__ srcs, const float* __restrict__ statsEnc,
                             const float* __restrict__ g, const float* __restrict__ bb,
                             float* __restrict__ agg) {
  __shared__ float ssc[cENC], ssh[cENC];
  int tid = threadIdx.x;
  if (tid < cENC) {
    float m = statsEnc[tid] * INV_NLOW;
    float var = statsEnc[cENC + tid] * INV_NLOW - m * m;
    float sc = g[tid] * rsqrtf(var + cEPS);
    ssc[tid] = sc;
    ssh[tid] = bb[tid] - m * sc;
  }
  __syncthreads();
  int c = tid & 31;
  int n = blockIdx.x * 8 + (tid >> 5);
  int lo = rowptr[n], hi = rowptr[n + 1];
  float sum = 0.0f;
  int i = lo;
  for (; i + 1 < hi; i += 2) {
    int s0 = srcs[i], s1 = srcs[i + 1];
    sum += enc[(size_t)s0 * cENC + c] + enc[(size_t)s1 * cENC + c];
  }
  if (i < hi) sum += enc[(size_t)srcs[i] * cENC + c];
  float deg = (float)(hi - lo);
  agg[(size_t)n * cENC + c] = (ssc[c] * sum + deg * ssh[c]) / fmaxf(deg, 1.0f);
}

// ---------------- down-projection + BN0 stats ----------------
__global__ void k_down(const float* __restrict__ agg,
                       const float* __restrict__ z_std, const float* __restrict__ land,
                       const float* __restrict__ Wrel, const float* __restrict__ brel,
                       const float* __restrict__ Wroot,
                       float* __restrict__ x0, float* __restrict__ stats) {
  __shared__ float sstat[2 * cD];
  __shared__ float sWrel[cD * cENC], sWroot[cD * cHIGH_IN], sbrel[cD];
  int tid = threadIdx.x;
  if (tid < 2 * cD) sstat[tid] = 0.0f;
  for (int i = tid; i < cD * cENC; i += 256) sWrel[i] = Wrel[i];
  if (tid < cD * cHIGH_IN) sWroot[tid] = Wroot[tid];
  if (tid < cD) sbrel[tid] = brel[tid];
  __syncthreads();

  int n = blockIdx.x * 256 + tid;
  bool valid = n < cN_HIGH;
  float a[cENC], zz[cHIGH_IN];
  if (valid) {
    const float4* ar4 = (const float4*)(agg + (size_t)n * cENC);
    #pragma unroll
    for (int k = 0; k < cENC / 4; ++k) {
      float4 t4 = ar4[k];
      a[4*k] = t4.x; a[4*k+1] = t4.y; a[4*k+2] = t4.z; a[4*k+3] = t4.w;
    }
    #pragma unroll
    for (int k = 0; k < 6; ++k) zz[k] = z_std[(size_t)n * 6 + k];
    zz[6] = land[n];
  } else {
    #pragma unroll
    for (int k = 0; k < cENC; ++k) a[k] = 0.0f;
    #pragma unroll
    for (int k = 0; k < cHIGH_IN; ++k) zz[k] = 0.0f;
  }
  int lane = tid & 63;
  #pragma unroll
  for (int d = 0; d < cD; ++d) {
    float acc = sbrel[d];
    #pragma unroll
    for (int k = 0; k < cENC; ++k) acc += a[k] * sWrel[d * cENC + k];
    #pragma unroll
    for (int k = 0; k < cHIGH_IN; ++k) acc += zz[k] * sWroot[d * cHIGH_IN + k];
    if (valid) x0[(size_t)n * cD + d] = acc;
    float v = valid ? acc : 0.0f;
    float s1 = v, s2 = v * v;
    #pragma unroll
    for (int o = 32; o > 0; o >>= 1) { s1 += __shfl_down(s1, o); s2 += __shfl_down(s2, o); }
    if (lane == 0) { atomicAdd(&sstat[d], s1); atomicAdd(&sstat[cD + d], s2); }
  }
  __syncthreads();
  if (tid < 2 * cD) atomicAdd(&stats[tid], sstat[tid]);
}

// ---------------- GAT node transform (also emits bf16 xl rows) ----------------
__global__ void k_transform(const float* __restrict__ xin, const float* __restrict__ stats,
                            const float* __restrict__ g, const float* __restrict__ b,
                            const float* __restrict__ Wl, const float* __restrict__ bl,
                            const float* __restrict__ Wr, const float* __restrict__ br,
                            int applyRelu,
                            float* __restrict__ xl, float* __restrict__ xr,
                            unsigned short* __restrict__ xlb) {
  __shared__ float ssc[cD], ssh[cD], sWl[cD * cD], sWr[cD * cD], sbl[cD], sbr[cD];
  int tid = threadIdx.x;
  if (tid < cD) {
    float m = stats[tid] * INV_NHIGH;
    float v = stats[cD + tid] * INV_NHIGH - m * m;
    float sc = g[tid] * rsqrtf(v + cEPS);
    ssc[tid] = sc;
    ssh[tid] = b[tid] - m * sc;
    sbl[tid] = bl[tid];
    sbr[tid] = br[tid];
  }
  if (tid < cD * cD) { sWl[tid] = Wl[tid]; sWr[tid] = Wr[tid]; }
  __syncthreads();

  int n = blockIdx.x * 256 + tid;
  if (n >= cN_HIGH) return;
  float act[cD];
  const float* xp = xin + (size_t)n * cD;
  #pragma unroll
  for (int d = 0; d < cD; ++d) {
    float v = xp[d] * ssc[d] + ssh[d];
    if (applyRelu) v = fmaxf(v, 0.0f);
    act[d] = v;
  }
  float alv[cD];
  float* xlp = xl + (size_t)n * cD;
  float* xrp = xr + (size_t)n * cD;
  #pragma unroll
  for (int d = 0; d < cD; ++d) {
    float al = sbl[d], ar = sbr[d];
    #pragma unroll
    for (int k = 0; k < cD; ++k) { al += act[k] * sWl[d * cD + k]; ar += act[k] * sWr[d * cD + k]; }
    alv[d] = al;
    xlp[d] = al;
    xrp[d] = ar;
  }
  uint4 w0, w1;
  unsigned int* pw = (unsigned int*)&w0;
  #pragma unroll
  for (int k = 0; k < 4; ++k)
    pw[k] = f32_to_bf16_bits(alv[2 * k]) | (f32_to_bf16_bits(alv[2 * k + 1]) << 16);
  unsigned int* pw1 = (unsigned int*)&w1;
  #pragma unroll
  for (int k = 0; k < 4; ++k)
    pw1[k] = f32_to_bf16_bits(alv[8 + 2 * k]) | (f32_to_bf16_bits(alv[8 + 2 * k + 1]) << 16);
  uint4* dst = (uint4*)(xlb + (size_t)n * cD);
  dst[0] = w0;
  dst[1] = w1;
}

// ---------------- fused GAT edge pass v3: 2 lanes/node, 8 ch/lane ----------------
template<int FINAL>
__global__ __launch_bounds__(256)
void k_edge(const float* __restrict__ xl, const float* __restrict__ xr,
            const unsigned short* __restrict__ xlb,
            const int* __restrict__ rowptr, const int* __restrict__ srcs,
            const float* __restrict__ att, const float* __restrict__ bias,
            const float* __restrict__ pW, const float* __restrict__ pb,
            float* __restrict__ xout, float* __restrict__ stats,
            float* __restrict__ out) {
  __shared__ float sstat[2 * cD];
  int tid = threadIdx.x;
  if (!FINAL) {
    if (tid < 2 * cD) sstat[tid] = 0.0f;
    __syncthreads();
  }

  int half = tid & 1;
  int n = (blockIdx.x * 256 + tid) >> 1;
  bool valid = n < cN_HIGH;
  int base = half * 8;

  float av[8];
  #pragma unroll
  for (int k = 0; k < 8; ++k) av[k] = att[base + k];

  float xrv[8], num[8];
  float denom = 1.0f;
  int lo = 0, hi = 0;
  if (valid) {
    #pragma unroll
    for (int k = 0; k < 2; ++k) {
      float4 t = *(const float4*)(xr + (size_t)n * cD + base + 4 * k);
      xrv[4*k] = t.x; xrv[4*k+1] = t.y; xrv[4*k+2] = t.z; xrv[4*k+3] = t.w;
    }
    float xsv[8];
    #pragma unroll
    for (int k = 0; k < 2; ++k) {
      float4 t = *(const float4*)(xl + (size_t)n * cD + base + 4 * k);
      xsv[4*k] = t.x; xsv[4*k+1] = t.y; xsv[4*k+2] = t.z; xsv[4*k+3] = t.w;
    }
    float qa = 0.0f, qb = 0.0f;
    #pragma unroll
    for (int k = 0; k < 8; ++k) {
      float u = xsv[k] + xrv[k];
      u = fmaxf(u, cSLOPE * u);
      if (k & 1) qb += u * av[k]; else qa += u * av[k];
    }
    float qq = qa + qb;
    qq += __shfl_xor(qq, 1);
    float e = __expf(qq);
    denom = e;
    #pragma unroll
    for (int k = 0; k < 8; ++k) num[k] = e * xsv[k];
    lo = rowptr[n]; hi = rowptr[n + 1];
  } else {
    #pragma unroll
    for (int k = 0; k < 8; ++k) { num[k] = 0.0f; xrv[k] = 0.0f; }
  }

  const uint4* xl4 = (const uint4*)xlb;
  int i = lo;
  for (; i + 1 < hi; i += 2) {
    int s0 = srcs[i], s1 = srcs[i + 1];
    uint4 v0 = xl4[(size_t)s0 * 2 + half];
    uint4 v1 = xl4[(size_t)s1 * 2 + half];
    float x0[8], x1[8];
    unpack8(v0, x0);
    unpack8(v1, x1);
    float q0a = 0.0f, q0b = 0.0f, q1a = 0.0f, q1b = 0.0f;
    #pragma unroll
    for (int k = 0; k < 8; ++k) {
      float u0 = x0[k] + xrv[k]; u0 = fmaxf(u0, cSLOPE * u0);
      float u1 = x1[k] + xrv[k]; u1 = fmaxf(u1, cSLOPE * u1);
      if (k & 1) { q0b += u0 * av[k]; q1b += u1 * av[k]; }
      else       { q0a += u0 * av[k]; q1a += u1 * av[k]; }
    }
    float q0 = q0a + q0b, q1 = q1a + q1b;
    q0 += __shfl_xor(q0, 1);
    q1 += __shfl_xor(q1, 1);
    float e0 = __expf(q0), e1 = __expf(q1);
    denom += e0 + e1;
    #pragma unroll
    for (int k = 0; k < 8; ++k) num[k] += e0 * x0[k] + e1 * x1[k];
  }
  if (i < hi) {
    int s = srcs[i];
    uint4 v = xl4[(size_t)s * 2 + half];
    float x[8];
    unpack8(v, x);
    float qa = 0.0f, qb = 0.0f;
    #pragma unroll
    for (int k = 0; k < 8; ++k) {
      float u = x[k] + xrv[k]; u = fmaxf(u, cSLOPE * u);
      if (k & 1) qb += u * av[k]; else qa += u * av[k];
    }
    float qq = qa + qb;
    qq += __shfl_xor(qq, 1);
    float e = __expf(qq);
    denom += e;
    #pragma unroll
    for (int k = 0; k < 8; ++k) num[k] += e * x[k];
  }

  float cnt = (float)(hi - lo + 1);
  float inv = __builtin_amdgcn_rcpf(denom * cnt);
  float res[8];
  #pragma unroll
  for (int k = 0; k < 8; ++k)
    res[k] = valid ? (num[k] * inv + bias[base + k]) : 0.0f;

  if (FINAL) {
    float t = 0.0f;
    #pragma unroll
    for (int k = 0; k < 8; ++k) t += fmaxf(res[k], 0.0f) * pW[base + k];
    t += __shfl_xor(t, 1);
    if (valid && half == 0) out[n] = t + pb[0];
  } else {
    if (valid) {
      float4* op = (float4*)(xout + (size_t)n * cD + base);
      op[0] = make_float4(res[0], res[1], res[2], res[3]);
      op[1] = make_float4(res[4], res[5], res[6], res[7]);
    }
    #pragma unroll
    for (int k = 0; k < 8; ++k) {
      float s1 = res[k], s2 = res[k] * res[k];
      #pragma unroll
      for (int m = 2; m < 64; m <<= 1) { s1 += __shfl_xor(s1, m); s2 += __shfl_xor(s2, m); }
      if ((tid & 63) < 2) {
        atomicAdd(&sstat[base + k], s1);
        atomicAdd(&sstat[cD + base + k], s2);
      }
    }
    __syncthreads();
    if (tid < 2 * cD) atomicAdd(&stats[tid], sstat[tid]);
  }
}

// ---------------- launch ----------------
extern "C" void kernel_launch(void* const* d_in, const int* in_sizes, int n_in,
                              void* d_out, int out_size, void* d_ws, size_t ws_size,
                              hipStream_t stream) {
  const float* x_low    = (const float*)d_in[0];
  const float* z_std    = (const float*)d_in[1];
  const float* land     = (const float*)d_in[2];
  const int*   l2h_src  = (const int*)d_in[3];
  const int*   l2h_dst  = (const int*)d_in[4];
  const int*   hh_src   = (const int*)d_in[5];
  const int*   hh_dst   = (const int*)d_in[6];
  const float* gWih     = (const float*)d_in[7];
  const float* gWhh     = (const float*)d_in[8];
  const float* gbih     = (const float*)d_in[9];
  const float* gbhh     = (const float*)d_in[10];
  const float* dW       = (const float*)d_in[11];
  const float* db       = (const float*)d_in[12];
  const float* bn_enc_g = (const float*)d_in[13];
  const float* bn_enc_b = (const float*)d_in[14];
  const float* Wrel     = (const float*)d_in[15];
  const float* brel     = (const float*)d_in[16];
  const float* Wroot    = (const float*)d_in[17];
  const float* gat_Wl   = (const float*)d_in[18];
  const float* gat_bl   = (const float*)d_in[19];
  const float* gat_Wr   = (const float*)d_in[20];
  const float* gat_br   = (const float*)d_in[21];
  const float* gat_att  = (const float*)d_in[22];
  const float* gat_bias = (const float*)d_in[23];
  const float* bn_g     = (const float*)d_in[24];
  const float* bn_b     = (const float*)d_in[25];
  const float* pred_W   = (const float*)d_in[26];
  const float* pred_b   = (const float*)d_in[27];

  float* ws = (float*)d_ws;
  float* hs   = ws + OFF_HS;
  float* agg  = ws + OFF_AGG;
  float* enc  = ws + OFF_ENC;
  float* xA   = ws + OFF_XA;
  float* xB   = ws + OFF_XB;
  float* xl   = ws + OFF_XL;
  float* xr   = ws + OFF_XR;
  float* statsEnc = ws + OFF_STAT;
  float* statsX   = ws + OFF_STAT + 64;
  int* rp_hh  = (int*)(ws + OFF_RPH);
  int* src_hh = (int*)(ws + OFF_SRH);
  int* rp_l2h = (int*)(ws + OFF_RPL);
  int* src_l2h= (int*)(ws + OFF_SRL);
  int* cursor = (int*)(ws + OFF_CUR);
  int* part   = (int*)(ws + OFF_PART);
  unsigned short* xlb = (unsigned short*)(ws + OFF_XLB);

  hipMemsetAsync(statsEnc, 0, 256 * sizeof(float), stream);
  const int NODE_GRID = (cN_HIGH + 255) / 256;

  // --- CSR build: hh ---
  hipMemsetAsync(cursor, 0, cN_HIGH * sizeof(int), stream);
  k_hist<<<(cE_HH + 255) / 256, 256, 0, stream>>>(hh_dst, cE_HH, cursor);
  k_scan_local<<<SC_NB, 256, 0, stream>>>(cursor, cN_HIGH, rp_hh, part);
  k_scan_top<<<1, 256, 0, stream>>>(part, SC_NB, rp_hh + cN_HIGH);
  k_scan_add<<<SC_NB, 256, 0, stream>>>(rp_hh, part, cN_HIGH, cursor);
  k_scatter<<<(cE_HH + 255) / 256, 256, 0, stream>>>(hh_src, hh_dst, cE_HH, cursor, src_hh);
  // --- CSR build: l2h ---
  hipMemsetAsync(cursor, 0, cN_HIGH * sizeof(int), stream);
  k_hist<<<(cE_L2H + 255) / 256, 256, 0, stream>>>(l2h_dst, cE_L2H, cursor);
  k_scan_local<<<SC_NB, 256, 0, stream>>>(cursor, cN_HIGH, rp_l2h, part);
  k_scan_top<<<1, 256, 0, stream>>>(part, SC_NB, rp_l2h + cN_HIGH);
  k_scan_add<<<SC_NB, 256, 0, stream>>>(rp_l2h, part, cN_HIGH, cursor);
  k_scatter<<<(cE_L2H + 255) / 256, 256, 0, stream>>>(l2h_src, l2h_dst, cE_L2H, cursor, src_l2h);

  // --- encoder ---
  k_gru<<<cN_LOW / GN, GB, 0, stream>>>(x_low, gWih, gWhh, gbih, gbhh, hs);
  k_dense<<<cN_LOW / cDN, 256, 0, stream>>>(hs, dW, db, enc, statsEnc);
  k_gather_csr<<<cN_HIGH / 8, 256, 0, stream>>>(enc, rp_l2h, src_l2h, statsEnc,
                                                bn_enc_g, bn_enc_b, agg);
  k_down<<<NODE_GRID, 256, 0, stream>>>(agg, z_std, land, Wrel, brel, Wroot, xA, statsX);

  const int EDGE_GRID = (2 * cN_HIGH + 255) / 256;
  // --- 5 GATv2 layers ---
  for (int i = 0; i < cNL; ++i) {
    float* xin  = (i & 1) ? xB : xA;
    float* xout = (i & 1) ? xA : xB;
    k_transform<<<NODE_GRID, 256, 0, stream>>>(xin, statsX + 32 * i,
                                               bn_g + 16 * i, bn_b + 16 * i,
                                               gat_Wl + 256 * i, gat_bl + 16 * i,
                                               gat_Wr + 256 * i, gat_br + 16 * i,
                                               (i > 0) ? 1 : 0, xl, xr, xlb);
    if (i < cNL - 1) {
      k_edge<0><<<EDGE_GRID, 256, 0, stream>>>(xl, xr, xlb, rp_hh, src_hh,
                                               gat_att + 16 * i, gat_bias + 16 * i,
                                               nullptr, nullptr,
                                               xout, statsX + 32 * (i + 1), nullptr);
    } else {
      k_edge<1><<<EDGE_GRID, 256, 0, stream>>>(xl, xr, xlb, rp_hh, src_hh,
                                               gat_att + 16 * i, gat_bias + 16 * i,
                                               pred_W, pred_b,
                                               nullptr, nullptr, (float*)d_out);
    }
  }
}

// Round 14
// 939.603 us; speedup vs baseline: 1.9861x; 1.0111x over previous
//
#include <hip/hip_runtime.h>
#include <hip/hip_bf16.h>
#include <cstddef>

// ---------------- problem constants ----------------
constexpr int cN_LOW  = 20000;
constexpr int cN_HIGH = 150000;
constexpr int cSEQ = 25;
constexpr int cHIN = 25;
constexpr int cHHID = 25;
constexpr int cENC = 32;
constexpr int cHIGH_IN = 7;
constexpr int cD = 16;
constexpr int cNL = 5;
constexpr int cE_L2H = 1350000;
constexpr int cE_HH = 1200000;
constexpr float cEPS = 1e-5f;
constexpr float cSLOPE = 0.2f;
constexpr float INV_NLOW  = 1.0f / (float)cN_LOW;
constexpr float INV_NHIGH = 1.0f / (float)cN_HIGH;

constexpr int cHSP = 640;     // padded hs row stride: 10 exact 64-f chunks

// scan geometry
constexpr int SC_ELEM = 1024;
constexpr int SC_NB   = (cN_HIGH + SC_ELEM - 1) / SC_ELEM;     // 147
static_assert(SC_NB <= 256, "top scan assumes <=256 partials");

// ---------------- workspace layout (4-byte element offsets) ----------------
constexpr size_t OFF_HS   = 0;                                   // [N_LOW*640]
constexpr size_t SZ_HS    = (size_t)cN_LOW * cHSP;
constexpr size_t OFF_AGG  = 0;                                   // alias (hs dead after k_dense)
constexpr size_t OFF_ENC  = OFF_HS + SZ_HS;                      // [N_LOW*32]
constexpr size_t SZ_ENC   = (size_t)cN_LOW * cENC;
constexpr size_t OFF_XA   = OFF_ENC + SZ_ENC;
constexpr size_t OFF_XB   = OFF_XA + (size_t)cN_HIGH * cD;
constexpr size_t OFF_XL   = OFF_XB + (size_t)cN_HIGH * cD;
constexpr size_t OFF_XR   = OFF_XL + (size_t)cN_HIGH * cD;
constexpr size_t OFF_STAT = OFF_XR + (size_t)cN_HIGH * cD;       // [256]
constexpr size_t OFF_RPH  = OFF_STAT + 256;                      // rowptr_hh [N_HIGH+4]
constexpr size_t OFF_SRH  = OFF_RPH + cN_HIGH + 4;               // src_hh [E_HH]
constexpr size_t OFF_RPL  = OFF_SRH + cE_HH;                     // rowptr_l2h [N_HIGH+4]
constexpr size_t OFF_SRL  = OFF_RPL + cN_HIGH + 4;               // src_l2h [E_L2H]
constexpr size_t OFF_CUR  = OFF_SRL + cE_L2H;                    // cursor [N_HIGH]
constexpr size_t OFF_PART = OFF_CUR + cN_HIGH;                   // partials [256]
constexpr size_t OFF_XLB  = OFF_PART + 256;                      // xl bf16 [N_HIGH*16 ushort]

typedef _Float16 half_t;
typedef half_t half2_t __attribute__((ext_vector_type(2)));

__device__ __forceinline__ float fast_sigmoid(float a) {
  return __builtin_amdgcn_rcpf(1.0f + __expf(-a));
}
__device__ __forceinline__ float fast_tanh(float a) {
  float t = __expf(-2.0f * a);
  return (1.0f - t) * __builtin_amdgcn_rcpf(1.0f + t);
}
__device__ __forceinline__ unsigned int f32_to_bf16_bits(float f) {
  unsigned int u = __float_as_uint(f);
  return (u + 0x7FFFu + ((u >> 16) & 1u)) >> 16;     // RNE
}
__device__ __forceinline__ void unpack8(uint4 v, float* x) {
  const unsigned int* w = (const unsigned int*)&v;
  #pragma unroll
  for (int m = 0; m < 4; ++m) {
    x[2 * m]     = __uint_as_float(w[m] << 16);
    x[2 * m + 1] = __uint_as_float(w[m] & 0xFFFF0000u);
  }
}

// ---------------- GRU kernel v5: gate-split + fp16 dot2 weights ----------------
// r13 diagnosis: 84 fp32 weights/thread forced AGPR residency (VGPR_Count=60,
// no scratch traffic) -> extra v_accvgpr_read per use, ~300 instrs/wave-t.
// fp16-pack to 39 half2 regs + v_dot2_f32_f16 (2 MAC/instr, fp32 accum):
// ~70 instrs/wave-t. h recurrence value stays fp32 in-register; only dot
// inputs are fp16-rounded.
constexpr int GN = 5;                 // nodes per block
constexpr int GB = GN * 50;           // 250 threads

__global__ __launch_bounds__(256, 3)
void k_gru(const float* __restrict__ x_low,
           const float* __restrict__ Wih, const float* __restrict__ Whh,
           const float* __restrict__ bih, const float* __restrict__ bhh,
           float* __restrict__ hs) {
  __shared__ __align__(16) half_t sx16[2][GN][32];   // fp16 x rows (pad 25..31 = 0)
  __shared__ __align__(16) half_t sh16[2][GN][32];   // fp16 h rows
  __shared__ float sgi[GN][76];
  __shared__ float sgh[GN][76];

  int tid = threadIdx.x;
  int nl  = tid / 50;
  int rem = tid % 50;
  int s   = rem / 25;          // 0: x-side, 1: h-side
  int j   = rem % 25;
  int n   = blockIdx.x * GN + nl;

  const float* Wb = (s == 0) ? Wih : Whh;
  const float* bb = (s == 0) ? bih : bhh;
  half2_t w0[13], w1[13], w2[13];
  #pragma unroll
  for (int k = 0; k < 13; ++k) {
    int i0 = 2 * k, i1 = 2 * k + 1;
    float a0 = Wb[j * 25 + i0];                       // i0 <= 24 always
    float a1 = (i1 < 25) ? Wb[j * 25 + i1] : 0.0f;
    float b0v = Wb[(25 + j) * 25 + i0];
    float b1v = (i1 < 25) ? Wb[(25 + j) * 25 + i1] : 0.0f;
    float c0 = Wb[(50 + j) * 25 + i0];
    float c1 = (i1 < 25) ? Wb[(50 + j) * 25 + i1] : 0.0f;
    w0[k] = half2_t{(half_t)a0, (half_t)a1};
    w1[k] = half2_t{(half_t)b0v, (half_t)b1v};
    w2[k] = half2_t{(half_t)c0, (half_t)c1};
  }
  float b0 = bb[j], b1 = bb[25 + j], b2 = bb[50 + j];

  const float* xrow = x_low + (size_t)n * 625;
  float* hrow = hs + (size_t)n * cHSP;
  if (s == 0 && j < 15) hrow[625 + j] = 0.0f;       // zero hs pad for dense chunks

  // zero both fp16 buffers (covers pads and initial h=0)
  for (int i = tid; i < 2 * GN * 32; i += GB) {
    ((half_t*)sx16)[i] = (half_t)0.0f;
    ((half_t*)sh16)[i] = (half_t)0.0f;
  }
  __syncthreads();
  if (s == 0) sx16[0][nl][j] = (half_t)xrow[j];      // x for t=0
  __syncthreads();

  float hprev = 0.0f;                                // own h[j], fp32 (s==1 only)
  int p = 0, q = 0;
  for (int t = 0; t < cSEQ; ++t) {
    if (s == 0 && t + 1 < cSEQ)
      sx16[q ^ 1][nl][j] = (half_t)xrow[(t + 1) * 25 + j];
    const half2_t* vp = (const half2_t*)((s == 0) ? &sx16[q][nl][0] : &sh16[p][nl][0]);
    float g0 = b0, g1 = b1, g2 = b2;
    #pragma unroll
    for (int k = 0; k < 13; ++k) {
      half2_t v = vp[k];
      g0 = __builtin_amdgcn_fdot2(w0[k], v, g0, false);
      g1 = __builtin_amdgcn_fdot2(w1[k], v, g1, false);
      g2 = __builtin_amdgcn_fdot2(w2[k], v, g2, false);
    }
    float* gout = (s == 0) ? &sgi[nl][0] : &sgh[nl][0];
    gout[j] = g0; gout[25 + j] = g1; gout[50 + j] = g2;
    __syncthreads();
    if (s == 1) {
      float r  = fast_sigmoid(sgi[nl][j] + sgh[nl][j]);
      float z  = fast_sigmoid(sgi[nl][25 + j] + sgh[nl][25 + j]);
      float nn = fast_tanh(sgi[nl][50 + j] + r * sgh[nl][50 + j]);
      float hnew = (1.0f - z) * nn + z * hprev;
      hprev = hnew;
      sh16[p ^ 1][nl][j] = (half_t)hnew;
      hrow[t * 25 + j] = hnew;
    }
    p ^= 1; q ^= 1;
    __syncthreads();
  }
}

// ---------------- dense 625->32 + relu + BN stats (v4) ----------------
constexpr int cDN = 32;      // nodes per block
__global__ __launch_bounds__(256)
void k_dense(const float* __restrict__ hs, const float* __restrict__ W,
             const float* __restrict__ b, float* __restrict__ enc,
             float* __restrict__ statsEnc) {
  __shared__ __align__(16) float sW2[640 * 32];        // 80 KB: [f][e2-pair]
  __shared__ __align__(16) float sH[2][cDN * 68];      // 17.4 KB
  __shared__ float sstat[2 * cENC];
  int tid = threadIdx.x;
  for (int i = tid; i < 32 * 625; i += 256) {
    int e = i / 625, f = i % 625;
    sW2[f * 32 + (e & 15) * 2 + (e >> 4)] = W[i];
  }
  for (int i = tid; i < 32 * 15; i += 256)
    sW2[(625 + (i >> 5)) * 32 + (i & 31)] = 0.0f;
  if (tid < 2 * cENC) sstat[tid] = 0.0f;

  int e2 = tid & 15;
  int ng = (tid >> 4) & 3;
  int w  = tid >> 6;
  int rA = 8 * w + 2 * ng;
  int rB = rA + 1;
  size_t nbase = (size_t)blockIdx.x * cDN;

  int srow = tid >> 4;
  int sf4  = (tid & 15) * 4;
  const float* hsb = hs + nbase * cHSP;
  {
    float4 v0 = *(const float4*)(hsb + (size_t)srow * cHSP + sf4);
    float4 v1 = *(const float4*)(hsb + (size_t)(srow + 16) * cHSP + sf4);
    *(float4*)&sH[0][srow * 68 + sf4] = v0;
    *(float4*)&sH[0][(srow + 16) * 68 + sf4] = v1;
  }
  __syncthreads();

  float a00 = 0.0f, a01 = 0.0f, a10 = 0.0f, a11 = 0.0f;
  for (int c = 0; c < 10; ++c) {
    int buf = c & 1;
    if (c + 1 < 10) {
      const float* src = hsb + (c + 1) * 64;
      float4 v0 = *(const float4*)(src + (size_t)srow * cHSP + sf4);
      float4 v1 = *(const float4*)(src + (size_t)(srow + 16) * cHSP + sf4);
      *(float4*)&sH[buf ^ 1][srow * 68 + sf4] = v0;
      *(float4*)&sH[buf ^ 1][(srow + 16) * 68 + sf4] = v1;
    }
    const float* WC = sW2 + c * 64 * 32;
    #pragma unroll
    for (int fg = 0; fg < 16; ++fg) {
      float4 hA = *(const float4*)&sH[buf][rA * 68 + fg * 4];
      float4 hB = *(const float4*)&sH[buf][rB * 68 + fg * 4];
      const float* ha = (const float*)&hA;
      const float* hb = (const float*)&hB;
      #pragma unroll
      for (int k = 0; k < 4; ++k) {
        float2 wv = *(const float2*)&WC[(fg * 4 + k) * 32 + e2 * 2];
        a00 += wv.x * ha[k]; a01 += wv.y * ha[k];
        a10 += wv.x * hb[k]; a11 += wv.y * hb[k];
      }
    }
    __syncthreads();
  }
  float blo = b[e2], bhi = b[e2 + 16];
  float v00 = fmaxf(a00 + blo, 0.0f);
  float v01 = fmaxf(a01 + bhi, 0.0f);
  float v10 = fmaxf(a10 + blo, 0.0f);
  float v11 = fmaxf(a11 + bhi, 0.0f);
  size_t nA = nbase + rA, nB = nbase + rB;
  enc[nA * cENC + e2]      = v00;
  enc[nA * cENC + e2 + 16] = v01;
  enc[nB * cENC + e2]      = v10;
  enc[nB * cENC + e2 + 16] = v11;

  float s1lo = v00 + v10, s1hi = v01 + v11;
  float s2lo = v00 * v00 + v10 * v10, s2hi = v01 * v01 + v11 * v11;
  s1lo += __shfl_xor(s1lo, 16); s1hi += __shfl_xor(s1hi, 16);
  s2lo += __shfl_xor(s2lo, 16); s2hi += __shfl_xor(s2hi, 16);
  s1lo += __shfl_xor(s1lo, 32); s1hi += __shfl_xor(s1hi, 32);
  s2lo += __shfl_xor(s2lo, 32); s2hi += __shfl_xor(s2hi, 32);
  if ((tid & 63) < 16) {
    atomicAdd(&sstat[e2], s1lo);
    atomicAdd(&sstat[e2 + 16], s1hi);
    atomicAdd(&sstat[cENC + e2], s2lo);
    atomicAdd(&sstat[cENC + e2 + 16], s2hi);
  }
  __syncthreads();
  if (tid < 2 * cENC) atomicAdd(&statsEnc[tid], sstat[tid]);
}

// ---------------- CSR build ----------------
__global__ void k_hist(const int* __restrict__ dst, int nE, int* __restrict__ cnt) {
  int e = blockIdx.x * 256 + threadIdx.x;
  if (e < nE) atomicAdd(&cnt[dst[e]], 1);
}

__global__ void k_scan_local(const int* __restrict__ deg, int n,
                             int* __restrict__ out, int* __restrict__ partial) {
  int tid = threadIdx.x;
  int base = blockIdx.x * SC_ELEM + tid * 4;
  int4 v = make_int4(0, 0, 0, 0);
  if (base + 3 < n) v = *(const int4*)(deg + base);
  else { int* pv = (int*)&v; for (int k = 0; k < 4; ++k) if (base + k < n) pv[k] = deg[base + k]; }
  int tsum = v.x + v.y + v.z + v.w;
  int lane = tid & 63;
  int inc = tsum;
  #pragma unroll
  for (int o = 1; o < 64; o <<= 1) { int t = __shfl_up(inc, o); if (lane >= o) inc += t; }
  __shared__ int wtot[4];
  if (lane == 63) wtot[tid >> 6] = inc;
  __syncthreads();
  int w = tid >> 6, wbase = 0;
  #pragma unroll
  for (int k = 0; k < 3; ++k) if (k < w) wbase += wtot[k];
  int ebase = wbase + inc - tsum;
  int4 o4;
  o4.x = ebase; o4.y = ebase + v.x; o4.z = o4.y + v.y; o4.w = o4.z + v.z;
  if (base + 3 < n) *(int4*)(out + base) = o4;
  else { int* po = (int*)&o4; for (int k = 0; k < 4; ++k) if (base + k < n) out[base + k] = po[k]; }
  if (tid == 255) partial[blockIdx.x] = wbase + inc;
}

__global__ void k_scan_top(int* __restrict__ partial, int nb, int* __restrict__ total_out) {
  __shared__ int sd[256];
  int tid = threadIdx.x;
  int v = (tid < nb) ? partial[tid] : 0;
  sd[tid] = v;
  __syncthreads();
  for (int off = 1; off < 256; off <<= 1) {
    int t = (tid >= off) ? sd[tid - off] : 0;
    __syncthreads();
    sd[tid] += t;
    __syncthreads();
  }
  if (tid < nb) partial[tid] = sd[tid] - v;
  if (tid == 255) *total_out = sd[255];
}

__global__ void k_scan_add(int* __restrict__ rowptr, const int* __restrict__ partial,
                           int n, int* __restrict__ cursor) {
  int base = blockIdx.x * SC_ELEM + threadIdx.x * 4;
  int add = partial[blockIdx.x];
  if (base + 3 < n) {
    int4 v = *(int4*)(rowptr + base);
    v.x += add; v.y += add; v.z += add; v.w += add;
    *(int4*)(rowptr + base) = v;
    *(int4*)(cursor + base) = v;
  } else {
    for (int k = 0; k < 4; ++k)
      if (base + k < n) { int t = rowptr[base + k] + add; rowptr[base + k] = t; cursor[base + k] = t; }
  }
}

__global__ void k_scatter(const int* __restrict__ src, const int* __restrict__ dst, int nE,
                          int* __restrict__ cursor, int* __restrict__ out) {
  int e = blockIdx.x * 256 + threadIdx.x;
  if (e < nE) {
    int pos = atomicAdd(&cursor[dst[e]], 1);
    out[pos] = src[e];
  }
}

// ---------------- l2h gather via CSR (2-way unrolled) ----------------
__global__ void k_gather_csr(const float* __restrict__ enc, const int* __restrict__ rowptr,
                             const int* __restrict__ srcs, const float* __restrict__ statsEnc,
                             const float* __restrict__ g, const float* __restrict__ bb,
                             float* __restrict__ agg) {
  __shared__ float ssc[cENC], ssh[cENC];
  int tid = threadIdx.x;
  if (tid < cENC) {
    float m = statsEnc[tid] * INV_NLOW;
    float var = statsEnc[cENC + tid] * INV_NLOW - m * m;
    float sc = g[tid] * rsqrtf(var + cEPS);
    ssc[tid] = sc;
    ssh[tid] = bb[tid] - m * sc;
  }
  __syncthreads();
  int c = tid & 31;
  int n = blockIdx.x * 8 + (tid >> 5);
  int lo = rowptr[n], hi = rowptr[n + 1];
  float sum = 0.0f;
  int i = lo;
  for (; i + 1 < hi; i += 2) {
    int s0 = srcs[i], s1 = srcs[i + 1];
    sum += enc[(size_t)s0 * cENC + c] + enc[(size_t)s1 * cENC + c];
  }
  if (i < hi) sum += enc[(size_t)srcs[i] * cENC + c];
  float deg = (float)(hi - lo);
  agg[(size_t)n * cENC + c] = (ssc[c] * sum + deg * ssh[c]) / fmaxf(deg, 1.0f);
}

// ---------------- down-projection + BN0 stats ----------------
__global__ void k_down(const float* __restrict__ agg,
                       const float* __restrict__ z_std, const float* __restrict__ land,
                       const float* __restrict__ Wrel, const float* __restrict__ brel,
                       const float* __restrict__ Wroot,
                       float* __restrict__ x0, float* __restrict__ stats) {
  __shared__ float sstat[2 * cD];
  __shared__ float sWrel[cD * cENC], sWroot[cD * cHIGH_IN], sbrel[cD];
  int tid = threadIdx.x;
  if (tid < 2 * cD) sstat[tid] = 0.0f;
  for (int i = tid; i < cD * cENC; i += 256) sWrel[i] = Wrel[i];
  if (tid < cD * cHIGH_IN) sWroot[tid] = Wroot[tid];
  if (tid < cD) sbrel[tid] = brel[tid];
  __syncthreads();

  int n = blockIdx.x * 256 + tid;
  bool valid = n < cN_HIGH;
  float a[cENC], zz[cHIGH_IN];
  if (valid) {
    const float4* ar4 = (const float4*)(agg + (size_t)n * cENC);
    #pragma unroll
    for (int k = 0; k < cENC / 4; ++k) {
      float4 t4 = ar4[k];
      a[4*k] = t4.x; a[4*k+1] = t4.y; a[4*k+2] = t4.z; a[4*k+3] = t4.w;
    }
    #pragma unroll
    for (int k = 0; k < 6; ++k) zz[k] = z_std[(size_t)n * 6 + k];
    zz[6] = land[n];
  } else {
    #pragma unroll
    for (int k = 0; k < cENC; ++k) a[k] = 0.0f;
    #pragma unroll
    for (int k = 0; k < cHIGH_IN; ++k) zz[k] = 0.0f;
  }
  int lane = tid & 63;
  #pragma unroll
  for (int d = 0; d < cD; ++d) {
    float acc = sbrel[d];
    #pragma unroll
    for (int k = 0; k < cENC; ++k) acc += a[k] * sWrel[d * cENC + k];
    #pragma unroll
    for (int k = 0; k < cHIGH_IN; ++k) acc += zz[k] * sWroot[d * cHIGH_IN + k];
    if (valid) x0[(size_t)n * cD + d] = acc;
    float v = valid ? acc : 0.0f;
    float s1 = v, s2 = v * v;
    #pragma unroll
    for (int o = 32; o > 0; o >>= 1) { s1 += __shfl_down(s1, o); s2 += __shfl_down(s2, o); }
    if (lane == 0) { atomicAdd(&sstat[d], s1); atomicAdd(&sstat[cD + d], s2); }
  }
  __syncthreads();
  if (tid < 2 * cD) atomicAdd(&stats[tid], sstat[tid]);
}

// ---------------- GAT node transform (also emits bf16 xl rows) ----------------
__global__ void k_transform(const float* __restrict__ xin, const float* __restrict__ stats,
                            const float* __restrict__ g, const float* __restrict__ b,
                            const float* __restrict__ Wl, const float* __restrict__ bl,
                            const float* __restrict__ Wr, const float* __restrict__ br,
                            int applyRelu,
                            float* __restrict__ xl, float* __restrict__ xr,
                            unsigned short* __restrict__ xlb) {
  __shared__ float ssc[cD], ssh[cD], sWl[cD * cD], sWr[cD * cD], sbl[cD], sbr[cD];
  int tid = threadIdx.x;
  if (tid < cD) {
    float m = stats[tid] * INV_NHIGH;
    float v = stats[cD + tid] * INV_NHIGH - m * m;
    float sc = g[tid] * rsqrtf(v + cEPS);
    ssc[tid] = sc;
    ssh[tid] = b[tid] - m * sc;
    sbl[tid] = bl[tid];
    sbr[tid] = br[tid];
  }
  if (tid < cD * cD) { sWl[tid] = Wl[tid]; sWr[tid] = Wr[tid]; }
  __syncthreads();

  int n = blockIdx.x * 256 + tid;
  if (n >= cN_HIGH) return;
  float act[cD];
  const float* xp = xin + (size_t)n * cD;
  #pragma unroll
  for (int d = 0; d < cD; ++d) {
    float v = xp[d] * ssc[d] + ssh[d];
    if (applyRelu) v = fmaxf(v, 0.0f);
    act[d] = v;
  }
  float alv[cD];
  float* xlp = xl + (size_t)n * cD;
  float* xrp = xr + (size_t)n * cD;
  #pragma unroll
  for (int d = 0; d < cD; ++d) {
    float al = sbl[d], ar = sbr[d];
    #pragma unroll
    for (int k = 0; k < cD; ++k) { al += act[k] * sWl[d * cD + k]; ar += act[k] * sWr[d * cD + k]; }
    alv[d] = al;
    xlp[d] = al;
    xrp[d] = ar;
  }
  uint4 w0, w1;
  unsigned int* pw = (unsigned int*)&w0;
  #pragma unroll
  for (int k = 0; k < 4; ++k)
    pw[k] = f32_to_bf16_bits(alv[2 * k]) | (f32_to_bf16_bits(alv[2 * k + 1]) << 16);
  unsigned int* pw1 = (unsigned int*)&w1;
  #pragma unroll
  for (int k = 0; k < 4; ++k)
    pw1[k] = f32_to_bf16_bits(alv[8 + 2 * k]) | (f32_to_bf16_bits(alv[8 + 2 * k + 1]) << 16);
  uint4* dst = (uint4*)(xlb + (size_t)n * cD);
  dst[0] = w0;
  dst[1] = w1;
}

// ---------------- fused GAT edge pass v3: 2 lanes/node, 8 ch/lane ----------------
template<int FINAL>
__global__ __launch_bounds__(256)
void k_edge(const float* __restrict__ xl, const float* __restrict__ xr,
            const unsigned short* __restrict__ xlb,
            const int* __restrict__ rowptr, const int* __restrict__ srcs,
            const float* __restrict__ att, const float* __restrict__ bias,
            const float* __restrict__ pW, const float* __restrict__ pb,
            float* __restrict__ xout, float* __restrict__ stats,
            float* __restrict__ out) {
  __shared__ float sstat[2 * cD];
  int tid = threadIdx.x;
  if (!FINAL) {
    if (tid < 2 * cD) sstat[tid] = 0.0f;
    __syncthreads();
  }

  int half = tid & 1;
  int n = (blockIdx.x * 256 + tid) >> 1;
  bool valid = n < cN_HIGH;
  int base = half * 8;

  float av[8];
  #pragma unroll
  for (int k = 0; k < 8; ++k) av[k] = att[base + k];

  float xrv[8], num[8];
  float denom = 1.0f;
  int lo = 0, hi = 0;
  if (valid) {
    #pragma unroll
    for (int k = 0; k < 2; ++k) {
      float4 t = *(const float4*)(xr + (size_t)n * cD + base + 4 * k);
      xrv[4*k] = t.x; xrv[4*k+1] = t.y; xrv[4*k+2] = t.z; xrv[4*k+3] = t.w;
    }
    float xsv[8];
    #pragma unroll
    for (int k = 0; k < 2; ++k) {
      float4 t = *(const float4*)(xl + (size_t)n * cD + base + 4 * k);
      xsv[4*k] = t.x; xsv[4*k+1] = t.y; xsv[4*k+2] = t.z; xsv[4*k+3] = t.w;
    }
    float qa = 0.0f, qb = 0.0f;
    #pragma unroll
    for (int k = 0; k < 8; ++k) {
      float u = xsv[k] + xrv[k];
      u = fmaxf(u, cSLOPE * u);
      if (k & 1) qb += u * av[k]; else qa += u * av[k];
    }
    float qq = qa + qb;
    qq += __shfl_xor(qq, 1);
    float e = __expf(qq);
    denom = e;
    #pragma unroll
    for (int k = 0; k < 8; ++k) num[k] = e * xsv[k];
    lo = rowptr[n]; hi = rowptr[n + 1];
  } else {
    #pragma unroll
    for (int k = 0; k < 8; ++k) { num[k] = 0.0f; xrv[k] = 0.0f; }
  }

  const uint4* xl4 = (const uint4*)xlb;
  int i = lo;
  for (; i + 1 < hi; i += 2) {
    int s0 = srcs[i], s1 = srcs[i + 1];
    uint4 v0 = xl4[(size_t)s0 * 2 + half];
    uint4 v1 = xl4[(size_t)s1 * 2 + half];
    float x0[8], x1[8];
    unpack8(v0, x0);
    unpack8(v1, x1);
    float q0a = 0.0f, q0b = 0.0f, q1a = 0.0f, q1b = 0.0f;
    #pragma unroll
    for (int k = 0; k < 8; ++k) {
      float u0 = x0[k] + xrv[k]; u0 = fmaxf(u0, cSLOPE * u0);
      float u1 = x1[k] + xrv[k]; u1 = fmaxf(u1, cSLOPE * u1);
      if (k & 1) { q0b += u0 * av[k]; q1b += u1 * av[k]; }
      else       { q0a += u0 * av[k]; q1a += u1 * av[k]; }
    }
    float q0 = q0a + q0b, q1 = q1a + q1b;
    q0 += __shfl_xor(q0, 1);
    q1 += __shfl_xor(q1, 1);
    float e0 = __expf(q0), e1 = __expf(q1);
    denom += e0 + e1;
    #pragma unroll
    for (int k = 0; k < 8; ++k) num[k] += e0 * x0[k] + e1 * x1[k];
  }
  if (i < hi) {
    int s = srcs[i];
    uint4 v = xl4[(size_t)s * 2 + half];
    float x[8];
    unpack8(v, x);
    float qa = 0.0f, qb = 0.0f;
    #pragma unroll
    for (int k = 0; k < 8; ++k) {
      float u = x[k] + xrv[k]; u = fmaxf(u, cSLOPE * u);
      if (k & 1) qb += u * av[k]; else qa += u * av[k];
    }
    float qq = qa + qb;
    qq += __shfl_xor(qq, 1);
    float e = __expf(qq);
    denom += e;
    #pragma unroll
    for (int k = 0; k < 8; ++k) num[k] += e * x[k];
  }

  float cnt = (float)(hi - lo + 1);
  float inv = __builtin_amdgcn_rcpf(denom * cnt);
  float res[8];
  #pragma unroll
  for (int k = 0; k < 8; ++k)
    res[k] = valid ? (num[k] * inv + bias[base + k]) : 0.0f;

  if (FINAL) {
    float t = 0.0f;
    #pragma unroll
    for (int k = 0; k < 8; ++k) t += fmaxf(res[k], 0.0f) * pW[base + k];
    t += __shfl_xor(t, 1);
    if (valid && half == 0) out[n] = t + pb[0];
  } else {
    if (valid) {
      float4* op = (float4*)(xout + (size_t)n * cD + base);
      op[0] = make_float4(res[0], res[1], res[2], res[3]);
      op[1] = make_float4(res[4], res[5], res[6], res[7]);
    }
    #pragma unroll
    for (int k = 0; k < 8; ++k) {
      float s1 = res[k], s2 = res[k] * res[k];
      #pragma unroll
      for (int m = 2; m < 64; m <<= 1) { s1 += __shfl_xor(s1, m); s2 += __shfl_xor(s2, m); }
      if ((tid & 63) < 2) {
        atomicAdd(&sstat[base + k], s1);
        atomicAdd(&sstat[cD + base + k], s2);
      }
    }
    __syncthreads();
    if (tid < 2 * cD) atomicAdd(&stats[tid], sstat[tid]);
  }
}

// ---------------- launch ----------------
extern "C" void kernel_launch(void* const* d_in, const int* in_sizes, int n_in,
                              void* d_out, int out_size, void* d_ws, size_t ws_size,
                              hipStream_t stream) {
  const float* x_low    = (const float*)d_in[0];
  const float* z_std    = (const float*)d_in[1];
  const float* land     = (const float*)d_in[2];
  const int*   l2h_src  = (const int*)d_in[3];
  const int*   l2h_dst  = (const int*)d_in[4];
  const int*   hh_src   = (const int*)d_in[5];
  const int*   hh_dst   = (const int*)d_in[6];
  const float* gWih     = (const float*)d_in[7];
  const float* gWhh     = (const float*)d_in[8];
  const float* gbih     = (const float*)d_in[9];
  const float* gbhh     = (const float*)d_in[10];
  const float* dW       = (const float*)d_in[11];
  const float* db       = (const float*)d_in[12];
  const float* bn_enc_g = (const float*)d_in[13];
  const float* bn_enc_b = (const float*)d_in[14];
  const float* Wrel     = (const float*)d_in[15];
  const float* brel     = (const float*)d_in[16];
  const float* Wroot    = (const float*)d_in[17];
  const float* gat_Wl   = (const float*)d_in[18];
  const float* gat_bl   = (const float*)d_in[19];
  const float* gat_Wr   = (const float*)d_in[20];
  const float* gat_br   = (const float*)d_in[21];
  const float* gat_att  = (const float*)d_in[22];
  const float* gat_bias = (const float*)d_in[23];
  const float* bn_g     = (const float*)d_in[24];
  const float* bn_b     = (const float*)d_in[25];
  const float* pred_W   = (const float*)d_in[26];
  const float* pred_b   = (const float*)d_in[27];

  float* ws = (float*)d_ws;
  float* hs   = ws + OFF_HS;
  float* agg  = ws + OFF_AGG;
  float* enc  = ws + OFF_ENC;
  float* xA   = ws + OFF_XA;
  float* xB   = ws + OFF_XB;
  float* xl   = ws + OFF_XL;
  float* xr   = ws + OFF_XR;
  float* statsEnc = ws + OFF_STAT;
  float* statsX   = ws + OFF_STAT + 64;
  int* rp_hh  = (int*)(ws + OFF_RPH);
  int* src_hh = (int*)(ws + OFF_SRH);
  int* rp_l2h = (int*)(ws + OFF_RPL);
  int* src_l2h= (int*)(ws + OFF_SRL);
  int* cursor = (int*)(ws + OFF_CUR);
  int* part   = (int*)(ws + OFF_PART);
  unsigned short* xlb = (unsigned short*)(ws + OFF_XLB);

  hipMemsetAsync(statsEnc, 0, 256 * sizeof(float), stream);
  const int NODE_GRID = (cN_HIGH + 255) / 256;

  // --- CSR build: hh ---
  hipMemsetAsync(cursor, 0, cN_HIGH * sizeof(int), stream);
  k_hist<<<(cE_HH + 255) / 256, 256, 0, stream>>>(hh_dst, cE_HH, cursor);
  k_scan_local<<<SC_NB, 256, 0, stream>>>(cursor, cN_HIGH, rp_hh, part);
  k_scan_top<<<1, 256, 0, stream>>>(part, SC_NB, rp_hh + cN_HIGH);
  k_scan_add<<<SC_NB, 256, 0, stream>>>(rp_hh, part, cN_HIGH, cursor);
  k_scatter<<<(cE_HH + 255) / 256, 256, 0, stream>>>(hh_src, hh_dst, cE_HH, cursor, src_hh);
  // --- CSR build: l2h ---
  hipMemsetAsync(cursor, 0, cN_HIGH * sizeof(int), stream);
  k_hist<<<(cE_L2H + 255) / 256, 256, 0, stream>>>(l2h_dst, cE_L2H, cursor);
  k_scan_local<<<SC_NB, 256, 0, stream>>>(cursor, cN_HIGH, rp_l2h, part);
  k_scan_top<<<1, 256, 0, stream>>>(part, SC_NB, rp_l2h + cN_HIGH);
  k_scan_add<<<SC_NB, 256, 0, stream>>>(rp_l2h, part, cN_HIGH, cursor);
  k_scatter<<<(cE_L2H + 255) / 256, 256, 0, stream>>>(l2h_src, l2h_dst, cE_L2H, cursor, src_l2h);

  // --- encoder ---
  k_gru<<<cN_LOW / GN, GB, 0, stream>>>(x_low, gWih, gWhh, gbih, gbhh, hs);
  k_dense<<<cN_LOW / cDN, 256, 0, stream>>>(hs, dW, db, enc, statsEnc);
  k_gather_csr<<<cN_HIGH / 8, 256, 0, stream>>>(enc, rp_l2h, src_l2h, statsEnc,
                                                bn_enc_g, bn_enc_b, agg);
  k_down<<<NODE_GRID, 256, 0, stream>>>(agg, z_std, land, Wrel, brel, Wroot, xA, statsX);

  const int EDGE_GRID = (2 * cN_HIGH + 255) / 256;
  // --- 5 GATv2 layers ---
  for (int i = 0; i < cNL; ++i) {
    float* xin  = (i & 1) ? xB : xA;
    float* xout = (i & 1) ? xA : xB;
    k_transform<<<NODE_GRID, 256, 0, stream>>>(xin, statsX + 32 * i,
                                               bn_g + 16 * i, bn_b + 16 * i,
                                               gat_Wl + 256 * i, gat_bl + 16 * i,
                                               gat_Wr + 256 * i, gat_br + 16 * i,
                                               (i > 0) ? 1 : 0, xl, xr, xlb);
    if (i < cNL - 1) {
      k_edge<0><<<EDGE_GRID, 256, 0, stream>>>(xl, xr, xlb, rp_hh, src_hh,
                                               gat_att + 16 * i, gat_bias + 16 * i,
                                               nullptr, nullptr,
                                               xout, statsX + 32 * (i + 1), nullptr);
    } else {
      k_edge<1><<<EDGE_GRID, 256, 0, stream>>>(xl, xr, xlb, rp_hh, src_hh,
                                               gat_att + 16 * i, gat_bias + 16 * i,
                                               pred_W, pred_b,
                                               nullptr, nullptr, (float*)d_out);
    }
  }
}

// Round 15
// 912.221 us; speedup vs baseline: 2.0457x; 1.0300x over previous
//
#include <hip/hip_runtime.h>
#include <hip/hip_bf16.h>
#include <cstddef>

// ---------------- problem constants ----------------
constexpr int cN_LOW  = 20000;
constexpr int cN_HIGH = 150000;
constexpr int cSEQ = 25;
constexpr int cHIN = 25;
constexpr int cHHID = 25;
constexpr int cENC = 32;
constexpr int cHIGH_IN = 7;
constexpr int cD = 16;
constexpr int cNL = 5;
constexpr int cE_L2H = 1350000;
constexpr int cE_HH = 1200000;
constexpr float cEPS = 1e-5f;
constexpr float cSLOPE = 0.2f;
constexpr float INV_NLOW  = 1.0f / (float)cN_LOW;
constexpr float INV_NHIGH = 1.0f / (float)cN_HIGH;

constexpr int cHSP = 640;     // padded hs row stride: 10 exact 64-f chunks

// scan geometry
constexpr int SC_ELEM = 1024;
constexpr int SC_NB   = (cN_HIGH + SC_ELEM - 1) / SC_ELEM;     // 147
static_assert(SC_NB <= 256, "top scan assumes <=256 partials");

// ---------------- workspace layout (4-byte element offsets) ----------------
constexpr size_t OFF_HS   = 0;                                   // [N_LOW*640]
constexpr size_t SZ_HS    = (size_t)cN_LOW * cHSP;
constexpr size_t OFF_AGG  = 0;                                   // alias (hs dead after k_dense)
constexpr size_t OFF_ENC  = OFF_HS + SZ_HS;                      // [N_LOW*32]
constexpr size_t SZ_ENC   = (size_t)cN_LOW * cENC;
constexpr size_t OFF_XA   = OFF_ENC + SZ_ENC;
constexpr size_t OFF_XB   = OFF_XA + (size_t)cN_HIGH * cD;
constexpr size_t OFF_XL   = OFF_XB + (size_t)cN_HIGH * cD;
constexpr size_t OFF_XR   = OFF_XL + (size_t)cN_HIGH * cD;
constexpr size_t OFF_STAT = OFF_XR + (size_t)cN_HIGH * cD;       // [256]
constexpr size_t OFF_RPH  = OFF_STAT + 256;                      // rowptr_hh [N_HIGH+4]
constexpr size_t OFF_SRH  = OFF_RPH + cN_HIGH + 4;               // src_hh [E_HH]
constexpr size_t OFF_RPL  = OFF_SRH + cE_HH;                     // rowptr_l2h [N_HIGH+4]
constexpr size_t OFF_SRL  = OFF_RPL + cN_HIGH + 4;               // src_l2h [E_L2H]
constexpr size_t OFF_CUR  = OFF_SRL + cE_L2H;                    // cursor [N_HIGH]
constexpr size_t OFF_PART = OFF_CUR + cN_HIGH;                   // partials [256]
constexpr size_t OFF_XLB  = OFF_PART + 256;                      // xl bf16 [N_HIGH*16 ushort]

typedef _Float16 half_t;
typedef half_t half2_t __attribute__((ext_vector_type(2)));

__device__ __forceinline__ float fast_sigmoid(float a) {
  return __builtin_amdgcn_rcpf(1.0f + __expf(-a));
}
__device__ __forceinline__ float fast_tanh(float a) {
  float t = __expf(-2.0f * a);
  return (1.0f - t) * __builtin_amdgcn_rcpf(1.0f + t);
}
__device__ __forceinline__ unsigned int f32_to_bf16_bits(float f) {
  unsigned int u = __float_as_uint(f);
  return (u + 0x7FFFu + ((u >> 16) & 1u)) >> 16;     // RNE
}
__device__ __forceinline__ void unpack8(uint4 v, float* x) {
  const unsigned int* w = (const unsigned int*)&v;
  #pragma unroll
  for (int m = 0; m < 4; ++m) {
    x[2 * m]     = __uint_as_float(w[m] << 16);
    x[2 * m + 1] = __uint_as_float(w[m] & 0xFFFF0000u);
  }
}

// ---------------- GRU kernel v6: one node per wave, ZERO barriers ----------------
// r14 diagnosis: 48% VALUBusy at 38% occupancy = stalls on the 2x/t
// __syncthreads + cross-wave LDS gate exchange. Now lanes 0-24 = x-side,
// lanes 32-56 = h-side of the SAME wave: gate exchange is one shfl_xor(32),
// x/h rows are wave-private 64B LDS rows (intra-wave ds ordering, no
// s_barrier anywhere in the t-loop). fp16 fdot2 weights kept from r14.
constexpr int GW = 4;                 // nodes (waves) per block

__global__ __launch_bounds__(256, 3)
void k_gru(const float* __restrict__ x_low,
           const float* __restrict__ Wih, const float* __restrict__ Whh,
           const float* __restrict__ bih, const float* __restrict__ bhh,
           float* __restrict__ hs) {
  __shared__ __align__(16) half_t sx16[2][GW][32];
  __shared__ __align__(16) half_t sh16[2][GW][32];

  int tid  = threadIdx.x;
  int wv   = tid >> 6;          // wave in block, 0..3
  int lane = tid & 63;
  int s    = (lane >= 32) ? 1 : 0;
  int j    = lane - 32 * s;     // 0..31; active if < 25
  bool act = j < 25;
  int n    = blockIdx.x * GW + wv;

  const float* Wb = s ? Whh : Wih;
  const float* bb = s ? bhh : bih;
  half2_t w0[13], w1[13], w2[13];
  float b0 = 0.0f, b1 = 0.0f, b2 = 0.0f;
  if (act) {
    #pragma unroll
    for (int k = 0; k < 13; ++k) {
      int i0 = 2 * k, i1 = 2 * k + 1;
      float a0 = Wb[j * 25 + i0];
      float a1 = (i1 < 25) ? Wb[j * 25 + i1] : 0.0f;
      float c0 = Wb[(25 + j) * 25 + i0];
      float c1 = (i1 < 25) ? Wb[(25 + j) * 25 + i1] : 0.0f;
      float d0 = Wb[(50 + j) * 25 + i0];
      float d1 = (i1 < 25) ? Wb[(50 + j) * 25 + i1] : 0.0f;
      w0[k] = half2_t{(half_t)a0, (half_t)a1};
      w1[k] = half2_t{(half_t)c0, (half_t)c1};
      w2[k] = half2_t{(half_t)d0, (half_t)d1};
    }
    b0 = bb[j]; b1 = bb[25 + j]; b2 = bb[50 + j];
  } else {
    #pragma unroll
    for (int k = 0; k < 13; ++k) { w0[k] = half2_t{(half_t)0.0f, (half_t)0.0f};
      w1[k] = w0[k]; w2[k] = w0[k]; }
  }

  const float* xrow = x_low + (size_t)n * 625;
  float* hrow = hs + (size_t)n * cHSP;
  if (!s && j < 15) hrow[625 + j] = 0.0f;      // zero hs pad for dense chunks

  // zero wave-private LDS rows (pads included); intra-wave ordering only
  if (!s) { sx16[0][wv][lane] = (half_t)0.0f; sx16[1][wv][lane] = (half_t)0.0f; }
  else    { sh16[0][wv][lane - 32] = (half_t)0.0f; sh16[1][wv][lane - 32] = (half_t)0.0f; }
  if (!s && act) sx16[0][wv][j] = (half_t)xrow[j];   // x for t=0

  float hprev = 0.0f;
  int p = 0, q = 0;
  for (int t = 0; t < cSEQ; ++t) {
    if (!s && act && t + 1 < cSEQ)
      sx16[q ^ 1][wv][j] = (half_t)xrow[(t + 1) * 25 + j];
    const half2_t* vp = (const half2_t*)(s ? &sh16[p][wv][0] : &sx16[q][wv][0]);
    float g0 = b0, g1 = b1, g2 = b2;
    #pragma unroll
    for (int k = 0; k < 13; ++k) {
      half2_t v = vp[k];
      g0 = __builtin_amdgcn_fdot2(w0[k], v, g0, false);
      g1 = __builtin_amdgcn_fdot2(w1[k], v, g1, false);
      g2 = __builtin_amdgcn_fdot2(w2[k], v, g2, false);
    }
    // exchange: h-side lane 32+j receives x-side lane j's gates
    float gi0 = __shfl_xor(g0, 32);
    float gi1 = __shfl_xor(g1, 32);
    float gi2 = __shfl_xor(g2, 32);
    if (s && act) {
      float r  = fast_sigmoid(gi0 + g0);
      float z  = fast_sigmoid(gi1 + g1);
      float nn = fast_tanh(gi2 + r * g2);
      float hnew = (1.0f - z) * nn + z * hprev;
      hprev = hnew;
      sh16[p ^ 1][wv][j] = (half_t)hnew;
      hrow[t * 25 + j] = hnew;
    }
    p ^= 1; q ^= 1;
  }
}

// ---------------- dense 625->32 + relu + BN stats (v4) ----------------
constexpr int cDN = 32;      // nodes per block
__global__ __launch_bounds__(256)
void k_dense(const float* __restrict__ hs, const float* __restrict__ W,
             const float* __restrict__ b, float* __restrict__ enc,
             float* __restrict__ statsEnc) {
  __shared__ __align__(16) float sW2[640 * 32];        // 80 KB: [f][e2-pair]
  __shared__ __align__(16) float sH[2][cDN * 68];      // 17.4 KB
  __shared__ float sstat[2 * cENC];
  int tid = threadIdx.x;
  for (int i = tid; i < 32 * 625; i += 256) {
    int e = i / 625, f = i % 625;
    sW2[f * 32 + (e & 15) * 2 + (e >> 4)] = W[i];
  }
  for (int i = tid; i < 32 * 15; i += 256)
    sW2[(625 + (i >> 5)) * 32 + (i & 31)] = 0.0f;
  if (tid < 2 * cENC) sstat[tid] = 0.0f;

  int e2 = tid & 15;
  int ng = (tid >> 4) & 3;
  int w  = tid >> 6;
  int rA = 8 * w + 2 * ng;
  int rB = rA + 1;
  size_t nbase = (size_t)blockIdx.x * cDN;

  int srow = tid >> 4;
  int sf4  = (tid & 15) * 4;
  const float* hsb = hs + nbase * cHSP;
  {
    float4 v0 = *(const float4*)(hsb + (size_t)srow * cHSP + sf4);
    float4 v1 = *(const float4*)(hsb + (size_t)(srow + 16) * cHSP + sf4);
    *(float4*)&sH[0][srow * 68 + sf4] = v0;
    *(float4*)&sH[0][(srow + 16) * 68 + sf4] = v1;
  }
  __syncthreads();

  float a00 = 0.0f, a01 = 0.0f, a10 = 0.0f, a11 = 0.0f;
  for (int c = 0; c < 10; ++c) {
    int buf = c & 1;
    if (c + 1 < 10) {
      const float* src = hsb + (c + 1) * 64;
      float4 v0 = *(const float4*)(src + (size_t)srow * cHSP + sf4);
      float4 v1 = *(const float4*)(src + (size_t)(srow + 16) * cHSP + sf4);
      *(float4*)&sH[buf ^ 1][srow * 68 + sf4] = v0;
      *(float4*)&sH[buf ^ 1][(srow + 16) * 68 + sf4] = v1;
    }
    const float* WC = sW2 + c * 64 * 32;
    #pragma unroll
    for (int fg = 0; fg < 16; ++fg) {
      float4 hA = *(const float4*)&sH[buf][rA * 68 + fg * 4];
      float4 hB = *(const float4*)&sH[buf][rB * 68 + fg * 4];
      const float* ha = (const float*)&hA;
      const float* hb = (const float*)&hB;
      #pragma unroll
      for (int k = 0; k < 4; ++k) {
        float2 wv = *(const float2*)&WC[(fg * 4 + k) * 32 + e2 * 2];
        a00 += wv.x * ha[k]; a01 += wv.y * ha[k];
        a10 += wv.x * hb[k]; a11 += wv.y * hb[k];
      }
    }
    __syncthreads();
  }
  float blo = b[e2], bhi = b[e2 + 16];
  float v00 = fmaxf(a00 + blo, 0.0f);
  float v01 = fmaxf(a01 + bhi, 0.0f);
  float v10 = fmaxf(a10 + blo, 0.0f);
  float v11 = fmaxf(a11 + bhi, 0.0f);
  size_t nA = nbase + rA, nB = nbase + rB;
  enc[nA * cENC + e2]      = v00;
  enc[nA * cENC + e2 + 16] = v01;
  enc[nB * cENC + e2]      = v10;
  enc[nB * cENC + e2 + 16] = v11;

  float s1lo = v00 + v10, s1hi = v01 + v11;
  float s2lo = v00 * v00 + v10 * v10, s2hi = v01 * v01 + v11 * v11;
  s1lo += __shfl_xor(s1lo, 16); s1hi += __shfl_xor(s1hi, 16);
  s2lo += __shfl_xor(s2lo, 16); s2hi += __shfl_xor(s2hi, 16);
  s1lo += __shfl_xor(s1lo, 32); s1hi += __shfl_xor(s1hi, 32);
  s2lo += __shfl_xor(s2lo, 32); s2hi += __shfl_xor(s2hi, 32);
  if ((tid & 63) < 16) {
    atomicAdd(&sstat[e2], s1lo);
    atomicAdd(&sstat[e2 + 16], s1hi);
    atomicAdd(&sstat[cENC + e2], s2lo);
    atomicAdd(&sstat[cENC + e2 + 16], s2hi);
  }
  __syncthreads();
  if (tid < 2 * cENC) atomicAdd(&statsEnc[tid], sstat[tid]);
}

// ---------------- CSR build ----------------
__global__ void k_hist(const int* __restrict__ dst, int nE, int* __restrict__ cnt) {
  int e = blockIdx.x * 256 + threadIdx.x;
  if (e < nE) atomicAdd(&cnt[dst[e]], 1);
}

__global__ void k_scan_local(const int* __restrict__ deg, int n,
                             int* __restrict__ out, int* __restrict__ partial) {
  int tid = threadIdx.x;
  int base = blockIdx.x * SC_ELEM + tid * 4;
  int4 v = make_int4(0, 0, 0, 0);
  if (base + 3 < n) v = *(const int4*)(deg + base);
  else { int* pv = (int*)&v; for (int k = 0; k < 4; ++k) if (base + k < n) pv[k] = deg[base + k]; }
  int tsum = v.x + v.y + v.z + v.w;
  int lane = tid & 63;
  int inc = tsum;
  #pragma unroll
  for (int o = 1; o < 64; o <<= 1) { int t = __shfl_up(inc, o); if (lane >= o) inc += t; }
  __shared__ int wtot[4];
  if (lane == 63) wtot[tid >> 6] = inc;
  __syncthreads();
  int w = tid >> 6, wbase = 0;
  #pragma unroll
  for (int k = 0; k < 3; ++k) if (k < w) wbase += wtot[k];
  int ebase = wbase + inc - tsum;
  int4 o4;
  o4.x = ebase; o4.y = ebase + v.x; o4.z = o4.y + v.y; o4.w = o4.z + v.z;
  if (base + 3 < n) *(int4*)(out + base) = o4;
  else { int* po = (int*)&o4; for (int k = 0; k < 4; ++k) if (base + k < n) out[base + k] = po[k]; }
  if (tid == 255) partial[blockIdx.x] = wbase + inc;
}

__global__ void k_scan_top(int* __restrict__ partial, int nb, int* __restrict__ total_out) {
  __shared__ int sd[256];
  int tid = threadIdx.x;
  int v = (tid < nb) ? partial[tid] : 0;
  sd[tid] = v;
  __syncthreads();
  for (int off = 1; off < 256; off <<= 1) {
    int t = (tid >= off) ? sd[tid - off] : 0;
    __syncthreads();
    sd[tid] += t;
    __syncthreads();
  }
  if (tid < nb) partial[tid] = sd[tid] - v;
  if (tid == 255) *total_out = sd[255];
}

__global__ void k_scan_add(int* __restrict__ rowptr, const int* __restrict__ partial,
                           int n, int* __restrict__ cursor) {
  int base = blockIdx.x * SC_ELEM + threadIdx.x * 4;
  int add = partial[blockIdx.x];
  if (base + 3 < n) {
    int4 v = *(int4*)(rowptr + base);
    v.x += add; v.y += add; v.z += add; v.w += add;
    *(int4*)(rowptr + base) = v;
    *(int4*)(cursor + base) = v;
  } else {
    for (int k = 0; k < 4; ++k)
      if (base + k < n) { int t = rowptr[base + k] + add; rowptr[base + k] = t; cursor[base + k] = t; }
  }
}

__global__ void k_scatter(const int* __restrict__ src, const int* __restrict__ dst, int nE,
                          int* __restrict__ cursor, int* __restrict__ out) {
  int e = blockIdx.x * 256 + threadIdx.x;
  if (e < nE) {
    int pos = atomicAdd(&cursor[dst[e]], 1);
    out[pos] = src[e];
  }
}

// ---------------- l2h gather via CSR (2-way unrolled) ----------------
__global__ void k_gather_csr(const float* __restrict__ enc, const int* __restrict__ rowptr,
                             const int* __restrict__ srcs, const float* __restrict__ statsEnc,
                             const float* __restrict__ g, const float* __restrict__ bb,
                             float* __restrict__ agg) {
  __shared__ float ssc[cENC], ssh[cENC];
  int tid = threadIdx.x;
  if (tid < cENC) {
    float m = statsEnc[tid] * INV_NLOW;
    float var = statsEnc[cENC + tid] * INV_NLOW - m * m;
    float sc = g[tid] * rsqrtf(var + cEPS);
    ssc[tid] = sc;
    ssh[tid] = bb[tid] - m * sc;
  }
  __syncthreads();
  int c = tid & 31;
  int n = blockIdx.x * 8 + (tid >> 5);
  int lo = rowptr[n], hi = rowptr[n + 1];
  float sum = 0.0f;
  int i = lo;
  for (; i + 1 < hi; i += 2) {
    int s0 = srcs[i], s1 = srcs[i + 1];
    sum += enc[(size_t)s0 * cENC + c] + enc[(size_t)s1 * cENC + c];
  }
  if (i < hi) sum += enc[(size_t)srcs[i] * cENC + c];
  float deg = (float)(hi - lo);
  agg[(size_t)n * cENC + c] = (ssc[c] * sum + deg * ssh[c]) / fmaxf(deg, 1.0f);
}

// ---------------- down-projection + BN0 stats ----------------
__global__ void k_down(const float* __restrict__ agg,
                       const float* __restrict__ z_std, const float* __restrict__ land,
                       const float* __restrict__ Wrel, const float* __restrict__ brel,
                       const float* __restrict__ Wroot,
                       float* __restrict__ x0, float* __restrict__ stats) {
  __shared__ float sstat[2 * cD];
  __shared__ float sWrel[cD * cENC], sWroot[cD * cHIGH_IN], sbrel[cD];
  int tid = threadIdx.x;
  if (tid < 2 * cD) sstat[tid] = 0.0f;
  for (int i = tid; i < cD * cENC; i += 256) sWrel[i] = Wrel[i];
  if (tid < cD * cHIGH_IN) sWroot[tid] = Wroot[tid];
  if (tid < cD) sbrel[tid] = brel[tid];
  __syncthreads();

  int n = blockIdx.x * 256 + tid;
  bool valid = n < cN_HIGH;
  float a[cENC], zz[cHIGH_IN];
  if (valid) {
    const float4* ar4 = (const float4*)(agg + (size_t)n * cENC);
    #pragma unroll
    for (int k = 0; k < cENC / 4; ++k) {
      float4 t4 = ar4[k];
      a[4*k] = t4.x; a[4*k+1] = t4.y; a[4*k+2] = t4.z; a[4*k+3] = t4.w;
    }
    #pragma unroll
    for (int k = 0; k < 6; ++k) zz[k] = z_std[(size_t)n * 6 + k];
    zz[6] = land[n];
  } else {
    #pragma unroll
    for (int k = 0; k < cENC; ++k) a[k] = 0.0f;
    #pragma unroll
    for (int k = 0; k < cHIGH_IN; ++k) zz[k] = 0.0f;
  }
  int lane = tid & 63;
  #pragma unroll
  for (int d = 0; d < cD; ++d) {
    float acc = sbrel[d];
    #pragma unroll
    for (int k = 0; k < cENC; ++k) acc += a[k] * sWrel[d * cENC + k];
    #pragma unroll
    for (int k = 0; k < cHIGH_IN; ++k) acc += zz[k] * sWroot[d * cHIGH_IN + k];
    if (valid) x0[(size_t)n * cD + d] = acc;
    float v = valid ? acc : 0.0f;
    float s1 = v, s2 = v * v;
    #pragma unroll
    for (int o = 32; o > 0; o >>= 1) { s1 += __shfl_down(s1, o); s2 += __shfl_down(s2, o); }
    if (lane == 0) { atomicAdd(&sstat[d], s1); atomicAdd(&sstat[cD + d], s2); }
  }
  __syncthreads();
  if (tid < 2 * cD) atomicAdd(&stats[tid], sstat[tid]);
}

// ---------------- GAT node transform (also emits bf16 xl rows) ----------------
__global__ void k_transform(const float* __restrict__ xin, const float* __restrict__ stats,
                            const float* __restrict__ g, const float* __restrict__ b,
                            const float* __restrict__ Wl, const float* __restrict__ bl,
                            const float* __restrict__ Wr, const float* __restrict__ br,
                            int applyRelu,
                            float* __restrict__ xl, float* __restrict__ xr,
                            unsigned short* __restrict__ xlb) {
  __shared__ float ssc[cD], ssh[cD], sWl[cD * cD], sWr[cD * cD], sbl[cD], sbr[cD];
  int tid = threadIdx.x;
  if (tid < cD) {
    float m = stats[tid] * INV_NHIGH;
    float v = stats[cD + tid] * INV_NHIGH - m * m;
    float sc = g[tid] * rsqrtf(v + cEPS);
    ssc[tid] = sc;
    ssh[tid] = b[tid] - m * sc;
    sbl[tid] = bl[tid];
    sbr[tid] = br[tid];
  }
  if (tid < cD * cD) { sWl[tid] = Wl[tid]; sWr[tid] = Wr[tid]; }
  __syncthreads();

  int n = blockIdx.x * 256 + tid;
  if (n >= cN_HIGH) return;
  float act[cD];
  const float* xp = xin + (size_t)n * cD;
  #pragma unroll
  for (int d = 0; d < cD; ++d) {
    float v = xp[d] * ssc[d] + ssh[d];
    if (applyRelu) v = fmaxf(v, 0.0f);
    act[d] = v;
  }
  float alv[cD];
  float* xlp = xl + (size_t)n * cD;
  float* xrp = xr + (size_t)n * cD;
  #pragma unroll
  for (int d = 0; d < cD; ++d) {
    float al = sbl[d], ar = sbr[d];
    #pragma unroll
    for (int k = 0; k < cD; ++k) { al += act[k] * sWl[d * cD + k]; ar += act[k] * sWr[d * cD + k]; }
    alv[d] = al;
    xlp[d] = al;
    xrp[d] = ar;
  }
  uint4 w0, w1;
  unsigned int* pw = (unsigned int*)&w0;
  #pragma unroll
  for (int k = 0; k < 4; ++k)
    pw[k] = f32_to_bf16_bits(alv[2 * k]) | (f32_to_bf16_bits(alv[2 * k + 1]) << 16);
  unsigned int* pw1 = (unsigned int*)&w1;
  #pragma unroll
  for (int k = 0; k < 4; ++k)
    pw1[k] = f32_to_bf16_bits(alv[8 + 2 * k]) | (f32_to_bf16_bits(alv[8 + 2 * k + 1]) << 16);
  uint4* dst = (uint4*)(xlb + (size_t)n * cD);
  dst[0] = w0;
  dst[1] = w1;
}

// ---------------- fused GAT edge pass v3: 2 lanes/node, 8 ch/lane ----------------
template<int FINAL>
__global__ __launch_bounds__(256)
void k_edge(const float* __restrict__ xl, const float* __restrict__ xr,
            const unsigned short* __restrict__ xlb,
            const int* __restrict__ rowptr, const int* __restrict__ srcs,
            const float* __restrict__ att, const float* __restrict__ bias,
            const float* __restrict__ pW, const float* __restrict__ pb,
            float* __restrict__ xout, float* __restrict__ stats,
            float* __restrict__ out) {
  __shared__ float sstat[2 * cD];
  int tid = threadIdx.x;
  if (!FINAL) {
    if (tid < 2 * cD) sstat[tid] = 0.0f;
    __syncthreads();
  }

  int half = tid & 1;
  int n = (blockIdx.x * 256 + tid) >> 1;
  bool valid = n < cN_HIGH;
  int base = half * 8;

  float av[8];
  #pragma unroll
  for (int k = 0; k < 8; ++k) av[k] = att[base + k];

  float xrv[8], num[8];
  float denom = 1.0f;
  int lo = 0, hi = 0;
  if (valid) {
    #pragma unroll
    for (int k = 0; k < 2; ++k) {
      float4 t = *(const float4*)(xr + (size_t)n * cD + base + 4 * k);
      xrv[4*k] = t.x; xrv[4*k+1] = t.y; xrv[4*k+2] = t.z; xrv[4*k+3] = t.w;
    }
    float xsv[8];
    #pragma unroll
    for (int k = 0; k < 2; ++k) {
      float4 t = *(const float4*)(xl + (size_t)n * cD + base + 4 * k);
      xsv[4*k] = t.x; xsv[4*k+1] = t.y; xsv[4*k+2] = t.z; xsv[4*k+3] = t.w;
    }
    float qa = 0.0f, qb = 0.0f;
    #pragma unroll
    for (int k = 0; k < 8; ++k) {
      float u = xsv[k] + xrv[k];
      u = fmaxf(u, cSLOPE * u);
      if (k & 1) qb += u * av[k]; else qa += u * av[k];
    }
    float qq = qa + qb;
    qq += __shfl_xor(qq, 1);
    float e = __expf(qq);
    denom = e;
    #pragma unroll
    for (int k = 0; k < 8; ++k) num[k] = e * xsv[k];
    lo = rowptr[n]; hi = rowptr[n + 1];
  } else {
    #pragma unroll
    for (int k = 0; k < 8; ++k) { num[k] = 0.0f; xrv[k] = 0.0f; }
  }

  const uint4* xl4 = (const uint4*)xlb;
  int i = lo;
  for (; i + 1 < hi; i += 2) {
    int s0 = srcs[i], s1 = srcs[i + 1];
    uint4 v0 = xl4[(size_t)s0 * 2 + half];
    uint4 v1 = xl4[(size_t)s1 * 2 + half];
    float x0[8], x1[8];
    unpack8(v0, x0);
    unpack8(v1, x1);
    float q0a = 0.0f, q0b = 0.0f, q1a = 0.0f, q1b = 0.0f;
    #pragma unroll
    for (int k = 0; k < 8; ++k) {
      float u0 = x0[k] + xrv[k]; u0 = fmaxf(u0, cSLOPE * u0);
      float u1 = x1[k] + xrv[k]; u1 = fmaxf(u1, cSLOPE * u1);
      if (k & 1) { q0b += u0 * av[k]; q1b += u1 * av[k]; }
      else       { q0a += u0 * av[k]; q1a += u1 * av[k]; }
    }
    float q0 = q0a + q0b, q1 = q1a + q1b;
    q0 += __shfl_xor(q0, 1);
    q1 += __shfl_xor(q1, 1);
    float e0 = __expf(q0), e1 = __expf(q1);
    denom += e0 + e1;
    #pragma unroll
    for (int k = 0; k < 8; ++k) num[k] += e0 * x0[k] + e1 * x1[k];
  }
  if (i < hi) {
    int s = srcs[i];
    uint4 v = xl4[(size_t)s * 2 + half];
    float x[8];
    unpack8(v, x);
    float qa = 0.0f, qb = 0.0f;
    #pragma unroll
    for (int k = 0; k < 8; ++k) {
      float u = x[k] + xrv[k]; u = fmaxf(u, cSLOPE * u);
      if (k & 1) qb += u * av[k]; else qa += u * av[k];
    }
    float qq = qa + qb;
    qq += __shfl_xor(qq, 1);
    float e = __expf(qq);
    denom += e;
    #pragma unroll
    for (int k = 0; k < 8; ++k) num[k] += e * x[k];
  }

  float cnt = (float)(hi - lo + 1);
  float inv = __builtin_amdgcn_rcpf(denom * cnt);
  float res[8];
  #pragma unroll
  for (int k = 0; k < 8; ++k)
    res[k] = valid ? (num[k] * inv + bias[base + k]) : 0.0f;

  if (FINAL) {
    float t = 0.0f;
    #pragma unroll
    for (int k = 0; k < 8; ++k) t += fmaxf(res[k], 0.0f) * pW[base + k];
    t += __shfl_xor(t, 1);
    if (valid && half == 0) out[n] = t + pb[0];
  } else {
    if (valid) {
      float4* op = (float4*)(xout + (size_t)n * cD + base);
      op[0] = make_float4(res[0], res[1], res[2], res[3]);
      op[1] = make_float4(res[4], res[5], res[6], res[7]);
    }
    #pragma unroll
    for (int k = 0; k < 8; ++k) {
      float s1 = res[k], s2 = res[k] * res[k];
      #pragma unroll
      for (int m = 2; m < 64; m <<= 1) { s1 += __shfl_xor(s1, m); s2 += __shfl_xor(s2, m); }
      if ((tid & 63) < 2) {
        atomicAdd(&sstat[base + k], s1);
        atomicAdd(&sstat[cD + base + k], s2);
      }
    }
    __syncthreads();
    if (tid < 2 * cD) atomicAdd(&stats[tid], sstat[tid]);
  }
}

// ---------------- launch ----------------
extern "C" void kernel_launch(void* const* d_in, const int* in_sizes, int n_in,
                              void* d_out, int out_size, void* d_ws, size_t ws_size,
                              hipStream_t stream) {
  const float* x_low    = (const float*)d_in[0];
  const float* z_std    = (const float*)d_in[1];
  const float* land     = (const float*)d_in[2];
  const int*   l2h_src  = (const int*)d_in[3];
  const int*   l2h_dst  = (const int*)d_in[4];
  const int*   hh_src   = (const int*)d_in[5];
  const int*   hh_dst   = (const int*)d_in[6];
  const float* gWih     = (const float*)d_in[7];
  const float* gWhh     = (const float*)d_in[8];
  const float* gbih     = (const float*)d_in[9];
  const float* gbhh     = (const float*)d_in[10];
  const float* dW       = (const float*)d_in[11];
  const float* db       = (const float*)d_in[12];
  const float* bn_enc_g = (const float*)d_in[13];
  const float* bn_enc_b = (const float*)d_in[14];
  const float* Wrel     = (const float*)d_in[15];
  const float* brel     = (const float*)d_in[16];
  const float* Wroot    = (const float*)d_in[17];
  const float* gat_Wl   = (const float*)d_in[18];
  const float* gat_bl   = (const float*)d_in[19];
  const float* gat_Wr   = (const float*)d_in[20];
  const float* gat_br   = (const float*)d_in[21];
  const float* gat_att  = (const float*)d_in[22];
  const float* gat_bias = (const float*)d_in[23];
  const float* bn_g     = (const float*)d_in[24];
  const float* bn_b     = (const float*)d_in[25];
  const float* pred_W   = (const float*)d_in[26];
  const float* pred_b   = (const float*)d_in[27];

  float* ws = (float*)d_ws;
  float* hs   = ws + OFF_HS;
  float* agg  = ws + OFF_AGG;
  float* enc  = ws + OFF_ENC;
  float* xA   = ws + OFF_XA;
  float* xB   = ws + OFF_XB;
  float* xl   = ws + OFF_XL;
  float* xr   = ws + OFF_XR;
  float* statsEnc = ws + OFF_STAT;
  float* statsX   = ws + OFF_STAT + 64;
  int* rp_hh  = (int*)(ws + OFF_RPH);
  int* src_hh = (int*)(ws + OFF_SRH);
  int* rp_l2h = (int*)(ws + OFF_RPL);
  int* src_l2h= (int*)(ws + OFF_SRL);
  int* cursor = (int*)(ws + OFF_CUR);
  int* part   = (int*)(ws + OFF_PART);
  unsigned short* xlb = (unsigned short*)(ws + OFF_XLB);

  hipMemsetAsync(statsEnc, 0, 256 * sizeof(float), stream);
  const int NODE_GRID = (cN_HIGH + 255) / 256;

  // --- CSR build: hh ---
  hipMemsetAsync(cursor, 0, cN_HIGH * sizeof(int), stream);
  k_hist<<<(cE_HH + 255) / 256, 256, 0, stream>>>(hh_dst, cE_HH, cursor);
  k_scan_local<<<SC_NB, 256, 0, stream>>>(cursor, cN_HIGH, rp_hh, part);
  k_scan_top<<<1, 256, 0, stream>>>(part, SC_NB, rp_hh + cN_HIGH);
  k_scan_add<<<SC_NB, 256, 0, stream>>>(rp_hh, part, cN_HIGH, cursor);
  k_scatter<<<(cE_HH + 255) / 256, 256, 0, stream>>>(hh_src, hh_dst, cE_HH, cursor, src_hh);
  // --- CSR build: l2h ---
  hipMemsetAsync(cursor, 0, cN_HIGH * sizeof(int), stream);
  k_hist<<<(cE_L2H + 255) / 256, 256, 0, stream>>>(l2h_dst, cE_L2H, cursor);
  k_scan_local<<<SC_NB, 256, 0, stream>>>(cursor, cN_HIGH, rp_l2h, part);
  k_scan_top<<<1, 256, 0, stream>>>(part, SC_NB, rp_l2h + cN_HIGH);
  k_scan_add<<<SC_NB, 256, 0, stream>>>(rp_l2h, part, cN_HIGH, cursor);
  k_scatter<<<(cE_L2H + 255) / 256, 256, 0, stream>>>(l2h_src, l2h_dst, cE_L2H, cursor, src_l2h);

  // --- encoder ---
  k_gru<<<cN_LOW / GW, 256, 0, stream>>>(x_low, gWih, gWhh, gbih, gbhh, hs);
  k_dense<<<cN_LOW / cDN, 256, 0, stream>>>(hs, dW, db, enc, statsEnc);
  k_gather_csr<<<cN_HIGH / 8, 256, 0, stream>>>(enc, rp_l2h, src_l2h, statsEnc,
                                                bn_enc_g, bn_enc_b, agg);
  k_down<<<NODE_GRID, 256, 0, stream>>>(agg, z_std, land, Wrel, brel, Wroot, xA, statsX);

  const int EDGE_GRID = (2 * cN_HIGH + 255) / 256;
  // --- 5 GATv2 layers ---
  for (int i = 0; i < cNL; ++i) {
    float* xin  = (i & 1) ? xB : xA;
    float* xout = (i & 1) ? xA : xB;
    k_transform<<<NODE_GRID, 256, 0, stream>>>(xin, statsX + 32 * i,
                                               bn_g + 16 * i, bn_b + 16 * i,
                                               gat_Wl + 256 * i, gat_bl + 16 * i,
                                               gat_Wr + 256 * i, gat_br + 16 * i,
                                               (i > 0) ? 1 : 0, xl, xr, xlb);
    if (i < cNL - 1) {
      k_edge<0><<<EDGE_GRID, 256, 0, stream>>>(xl, xr, xlb, rp_hh, src_hh,
                                               gat_att + 16 * i, gat_bias + 16 * i,
                                               nullptr, nullptr,
                                               xout, statsX + 32 * (i + 1), nullptr);
    } else {
      k_edge<1><<<EDGE_GRID, 256, 0, stream>>>(xl, xr, xlb, rp_hh, src_hh,
                                               gat_att + 16 * i, gat_bias + 16 * i,
                                               pred_W, pred_b,
                                               nullptr, nullptr, (float*)d_out);
    }
  }
}